// Round 3
// baseline (172.679 us; speedup 1.0000x reference)
//
#include <hip/hip_runtime.h>
#include <math.h>

#define HWSZ 16384
#define CC   64
#define HH   128
#define WW   128
#define KS   7

typedef _Float16 half2v __attribute__((ext_vector_type(2)));
typedef _Float16 half4v __attribute__((ext_vector_type(4)));
typedef _Float16 half8v __attribute__((ext_vector_type(8)));
typedef float    f32x4  __attribute__((ext_vector_type(4)));

#define MFMA16(a, b, c) __builtin_amdgcn_mfma_f32_16x16x32_f16((a), (b), (c), 0, 0, 0)

// gelu tanh-form: max abs dev ~3e-4 vs erf, far under f16 rounding of H.
__device__ __forceinline__ float gelu_f(float v) {
    float z = v * (1.59576912f + 0.07135481f * v * v);
    float e = __expf(-z);
    return v * (1.f / (1.f + e));
}

__device__ __forceinline__ half8v cvt8(const float* p) {
    float4 a0 = *(const float4*)p, a1 = *(const float4*)(p + 4);
    return (half8v){(_Float16)a0.x, (_Float16)a0.y, (_Float16)a0.z, (_Float16)a0.w,
                    (_Float16)a1.x, (_Float16)a1.y, (_Float16)a1.z, (_Float16)a1.w};
}

// ============ SINGLE fused kernel: LN1+QKV (halo, in-block) + attn + proj + residual
//              + LN2 + MLP + NCHW store. grid 512 x 256, fully block-independent. ============
// LDS plan (smem[78216], 2 blocks/CU):
//   qkv-build era: kv_s@0(53312) q_s@53312(10240) | A@63552(9216) ps1c@72768 ps2c@73184
//                  lnw@73600 lnb@73856 qb@74112(768) | rpb@76352 sum@77704
//   attention era: kv_s q_s s_s@63552(12800) rpb sum
//   post-attn era: x2t@0(17408) ps1@20480 ps2@21504 m@22528 r@22784 w@23040 b@23296 pb@23552
//                  A2@53312(9216) f1b@63552 f2b@64576
//   MLP era:       H@17408(33792)  tr@17408(17408, after H reads)
__global__ __launch_bounds__(256) void k_block(
        const float* __restrict__ x,
        const float* __restrict__ qw,  const float* __restrict__ qb,
        const float* __restrict__ pw,  const float* __restrict__ pb,
        const float* __restrict__ rpb,
        const float* __restrict__ ln1w, const float* __restrict__ ln1b,
        const float* __restrict__ ln2w, const float* __restrict__ ln2b,
        const float* __restrict__ f1w, const float* __restrict__ f1b,
        const float* __restrict__ f2w, const float* __restrict__ f2b,
        float* __restrict__ out) {
    __shared__ __align__(16) char smem[78216];
    _Float16* kv_s  = (_Float16*)smem;                 // [196][136]
    _Float16* q_s   = (_Float16*)(smem + 53312);       // [64][80]
    _Float16* s_s   = (_Float16*)(smem + 63552);       // [128][50]
    float*    rpb_s = (float*)(smem + 76352);
    float*    sum_s = (float*)(smem + 77704);
    // qkv-build aliases (dead before scores written)
    _Float16* A_s   = (_Float16*)(smem + 63552);       // [64][72]
    float* ps1c  = (float*)(smem + 72768);             // [104]
    float* ps2c  = (float*)(smem + 73184);             // [104]
    float* lnw_s = (float*)(smem + 73600);             // [64]
    float* lnb_s = (float*)(smem + 73856);             // [64]
    float* qb_s  = (float*)(smem + 74112);             // [192]
    // post-attn aliases
    float* x2t  = (float*)smem;
    float* ps1  = (float*)(smem + 20480);
    float* ps2  = (float*)(smem + 21504);
    float* m_s  = (float*)(smem + 22528);
    float* r_s  = (float*)(smem + 22784);
    float* w_s  = (float*)(smem + 23040);
    float* b_s  = (float*)(smem + 23296);
    float* pb_s = (float*)(smem + 23552);
    _Float16* A2_s = (_Float16*)(smem + 53312);
    _Float16* H_s  = (_Float16*)(smem + 17408);
    float*    tr_s = (float*)(smem + 17408);
    float*    f1b_s = (float*)(smem + 63552);
    float*    f2b_s = (float*)(smem + 64576);

    int tid = threadIdx.x;
    int bx = blockIdx.x;
    int n  = bx >> 8;
    int th = (bx >> 4) & 15, tw = bx & 15;
    int h0 = th * 8, w0 = tw * 8;
    int wr0 = min(max(h0 - 3, 0), HH - 14);
    int ww0 = min(max(w0 - 3, 0), WW - 14);
    int lane = tid & 63, wvi = tid >> 6;
    int quad = lane >> 4, l16 = lane & 15;

    if (tid < 64) { lnw_s[tid] = ln1w[tid]; lnb_s[tid] = ln1b[tid]; }
    if (tid < 192) qb_s[tid] = qb[tid];
    for (int i = tid; i < 338; i += 256) rpb_s[i] = rpb[i];

    // qkv B-frags: f32 -> f16 once per wave (24 VGPRs, reused over 4 chunks)
    int nt0 = wvi * 48;
    half8v bq[3][2];
#pragma unroll
    for (int nf = 0; nf < 3; ++nf)
#pragma unroll
        for (int k2 = 0; k2 < 2; ++k2)
            bq[nf][k2] = cvt8(&qw[(size_t)(nt0 + nf * 16 + l16) * 64 + k2 * 32 + quad * 8]);

    // proj-weight prefetch (f32, 16 regs) — written to LDS as f16 after PV
    float4 pr0 = *(const float4*)&pw[tid * 8];
    float4 pr1 = *(const float4*)&pw[tid * 8 + 4];
    float4 pr2 = *(const float4*)&pw[2048 + tid * 8];
    float4 pr3 = *(const float4*)&pw[2048 + tid * 8 + 4];

    // ---- phase 1: LN1 + QKV for the 196-token halo, 4 chunks of 49 ----
    {
        int tkk = tid & 127, hfc = tid >> 7;
        const float qscale = 0.17677669529663687f;
        int base_ih = h0 - wr0, base_iw = w0 - ww0;
        for (int c = 0; c < 4; ++c) {
            float xv[32]; float s1v = 0.f, s2v = 0.f;
            if (tkk < 49) {
                int tok = c * 49 + tkk;
                int wi = tok / 14, wj = tok - wi * 14;
                const float* xp = x + (((size_t)(n * CC + hfc * 32)) << 14)
                                    + (wr0 + wi) * WW + (ww0 + wj);
#pragma unroll
                for (int e = 0; e < 32; ++e) {
                    float f = xp[(size_t)e << 14];
                    xv[e] = f; s1v += f; s2v += f * f;
                }
                ps1c[hfc * 52 + tkk] = s1v; ps2c[hfc * 52 + tkk] = s2v;
            }
            __syncthreads();            // ps ready; prev-chunk GEMM A-reads done
            if (tkk < 49) {
                float ss = ps1c[tkk] + ps1c[52 + tkk];
                float qq = ps2c[tkk] + ps2c[52 + tkk];
                float m = ss * (1.f / 64.f);
                float r = rsqrtf(qq * (1.f / 64.f) - m * m + 1e-5f);
#pragma unroll
                for (int u8 = 0; u8 < 4; ++u8) {
                    half8v o;
#pragma unroll
                    for (int e = 0; e < 8; ++e) {
                        int ch = hfc * 32 + u8 * 8 + e;
                        o[e] = (_Float16)((xv[u8 * 8 + e] - m) * r * lnw_s[ch] + lnb_s[ch]);
                    }
                    *(half8v*)&A_s[tkk * 72 + hfc * 32 + u8 * 8] = o;
                }
            }
            __syncthreads();            // A ready
            {
                f32x4 acc[4][3];
#pragma unroll
                for (int mf = 0; mf < 4; ++mf)
#pragma unroll
                    for (int nf = 0; nf < 3; ++nf) acc[mf][nf] = (f32x4){0.f, 0.f, 0.f, 0.f};
#pragma unroll
                for (int k2 = 0; k2 < 2; ++k2) {
                    half8v a[4];
#pragma unroll
                    for (int mf = 0; mf < 4; ++mf)
                        a[mf] = *(const half8v*)&A_s[(mf * 16 + l16) * 72 + k2 * 32 + quad * 8];
#pragma unroll
                    for (int mf = 0; mf < 4; ++mf)
#pragma unroll
                        for (int nf = 0; nf < 3; ++nf)
                            acc[mf][nf] = MFMA16(a[mf], bq[nf][k2], acc[mf][nf]);
                }
#pragma unroll
                for (int mf = 0; mf < 4; ++mf)
#pragma unroll
                    for (int nf = 0; nf < 3; ++nf) {
                        int j = nt0 + nf * 16 + l16;
                        float bias = qb_s[j];
                        if (j >= 64) {                       // k or v channel (uniform per nf)
#pragma unroll
                            for (int r = 0; r < 4; ++r) {
                                int tl = mf * 16 + quad * 4 + r;
                                if (tl < 49)
                                    kv_s[(c * 49 + tl) * 136 + (j - 64)] =
                                        (_Float16)(acc[mf][nf][r] + bias);
                            }
                        } else {                             // q channel: center tokens only
#pragma unroll
                            for (int r = 0; r < 4; ++r) {
                                int tl = mf * 16 + quad * 4 + r;
                                if (tl < 49) {
                                    int tq = c * 49 + tl;
                                    int qwi = tq / 14, qwj = tq - qwi * 14;
                                    int ih = qwi - base_ih, iw = qwj - base_iw;
                                    if ((unsigned)ih < 8u && (unsigned)iw < 8u)
                                        q_s[(ih * 8 + iw) * 80 + j] =
                                            (_Float16)((acc[mf][nf][r] + bias) * qscale);
                                }
                            }
                        }
                    }
            }
        }
    }
    __syncthreads();   // kv_s / q_s complete; A/ps/lnw/qb dead

    // ---- attention: QK^T + bias (identical math to previous rounds) ----
    int c16 = tid & 1, z = (tid >> 1) & 1, q = tid >> 2;
    int qy = q >> 3, qx = q & 7;
    int h = h0 + qy, wc = w0 + qx;
    int sh = min(max(h - 3, 0), HH - KS);
    int sw = min(max(wc - 3, 0), WW - KS);
    int oh = sh - wr0, ow = sw - ww0;
    int dhp = h - sh + 6, dwp = wc - sw + 6;
    {
        const half8v* qp = (const half8v*)&q_s[q * 80 + z * 32];
        half8v q0 = qp[0], q1 = qp[1], q2 = qp[2], q3 = qp[3];
        int i7 = 0, j7 = c16;
        for (int nb = c16; nb < 49; nb += 2) {
            int tok = (oh + i7) * 14 + (ow + j7);
            const half8v* kp = (const half8v*)&kv_s[tok * 136 + z * 32];
            half2v acc2 = { (_Float16)0.f, (_Float16)0.f };
            half8v k0 = kp[0], k1 = kp[1], k2 = kp[2], k3 = kp[3];
            acc2 += (half2v){k0.s0, k0.s1} * (half2v){q0.s0, q0.s1};
            acc2 += (half2v){k0.s2, k0.s3} * (half2v){q0.s2, q0.s3};
            acc2 += (half2v){k0.s4, k0.s5} * (half2v){q0.s4, q0.s5};
            acc2 += (half2v){k0.s6, k0.s7} * (half2v){q0.s6, q0.s7};
            acc2 += (half2v){k1.s0, k1.s1} * (half2v){q1.s0, q1.s1};
            acc2 += (half2v){k1.s2, k1.s3} * (half2v){q1.s2, q1.s3};
            acc2 += (half2v){k1.s4, k1.s5} * (half2v){q1.s4, q1.s5};
            acc2 += (half2v){k1.s6, k1.s7} * (half2v){q1.s6, q1.s7};
            acc2 += (half2v){k2.s0, k2.s1} * (half2v){q2.s0, q2.s1};
            acc2 += (half2v){k2.s2, k2.s3} * (half2v){q2.s2, q2.s3};
            acc2 += (half2v){k2.s4, k2.s5} * (half2v){q2.s4, q2.s5};
            acc2 += (half2v){k2.s6, k2.s7} * (half2v){q2.s6, q2.s7};
            acc2 += (half2v){k3.s0, k3.s1} * (half2v){q3.s0, q3.s1};
            acc2 += (half2v){k3.s2, k3.s3} * (half2v){q3.s2, q3.s3};
            acc2 += (half2v){k3.s4, k3.s5} * (half2v){q3.s4, q3.s5};
            acc2 += (half2v){k3.s6, k3.s7} * (half2v){q3.s6, q3.s7};
            float s = (float)acc2.x + (float)acc2.y
                    + rpb_s[(z * 13 + (dhp - i7)) * 13 + (dwp - j7)];
            s_s[(q * 2 + z) * 50 + nb] = (_Float16)s;
            j7 += 2;
            if (j7 >= 7) { j7 -= 7; ++i7; }
        }
    }
    __syncthreads();

    // softmax: 2 threads/row; unnormalized exp, 1/sum deferred to PV
    {
        int row = tid >> 1, h2 = tid & 1;
        _Float16* sp = &s_s[row * 50];
        int i0 = h2 ? 25 : 0, i1 = h2 ? 49 : 25;
        float mx = -1e30f;
        for (int i = i0; i < i1; ++i) mx = fmaxf(mx, (float)sp[i]);
        mx = fmaxf(mx, __shfl_xor(mx, 1));
        float sum = 0.f;
        for (int i = i0; i < i1; ++i) {
            float e = __expf((float)sp[i] - mx);
            sum += e;
            sp[i] = (_Float16)e;
        }
        sum += __shfl_xor(sum, 1);
        if (h2 == 0) sum_s[row] = 1.f / sum;
    }
    __syncthreads();

    // PV
    {
        const _Float16* pp = &s_s[(q * 2 + z) * 50];
        half2v acc[8];
#pragma unroll
        for (int j = 0; j < 8; ++j) acc[j] = (half2v){ (_Float16)0.f, (_Float16)0.f };
        int i7 = 0, j7 = 0;
        for (int nb = 0; nb < 49; ++nb) {
            int tok = (oh + i7) * 14 + (ow + j7);
            _Float16 p = pp[nb];
            half2v p2 = { p, p };
            const half8v* vp = (const half8v*)&kv_s[tok * 136 + 64 + z * 32 + c16 * 16];
            half8v v0 = vp[0], v1 = vp[1];
            acc[0] += (half2v){v0.s0, v0.s1} * p2;
            acc[1] += (half2v){v0.s2, v0.s3} * p2;
            acc[2] += (half2v){v0.s4, v0.s5} * p2;
            acc[3] += (half2v){v0.s6, v0.s7} * p2;
            acc[4] += (half2v){v1.s0, v1.s1} * p2;
            acc[5] += (half2v){v1.s2, v1.s3} * p2;
            acc[6] += (half2v){v1.s4, v1.s5} * p2;
            acc[7] += (half2v){v1.s6, v1.s7} * p2;
            ++j7;
            if (j7 == 7) { j7 = 0; ++i7; }
        }
        float inv = sum_s[q * 2 + z];
        _Float16* op = q_s + q * 72 + z * 32 + c16 * 16;
        half8v o0, o1;
#pragma unroll
        for (int j = 0; j < 4; ++j) {
            o0[2 * j]     = (_Float16)((float)acc[j].x * inv);
            o0[2 * j + 1] = (_Float16)((float)acc[j].y * inv);
            o1[2 * j]     = (_Float16)((float)acc[4 + j].x * inv);
            o1[2 * j + 1] = (_Float16)((float)acc[4 + j].y * inv);
        }
        *(half8v*)op = o0;
        *(half8v*)(op + 8) = o1;
    }
    __syncthreads();
    // proj weights: LDS writes from prefetched f32 regs (convert in reg)
    {
        int jj = tid >> 3, c8 = tid & 7;
        half8v w0v = {(_Float16)pr0.x, (_Float16)pr0.y, (_Float16)pr0.z, (_Float16)pr0.w,
                      (_Float16)pr1.x, (_Float16)pr1.y, (_Float16)pr1.z, (_Float16)pr1.w};
        half8v w1v = {(_Float16)pr2.x, (_Float16)pr2.y, (_Float16)pr2.z, (_Float16)pr2.w,
                      (_Float16)pr3.x, (_Float16)pr3.y, (_Float16)pr3.z, (_Float16)pr3.w};
        *(half8v*)&s_s[jj * 72 + c8 * 8] = w0v;
        *(half8v*)&s_s[(32 + jj) * 72 + c8 * 8] = w1v;
    }
    if (tid < 64) { w_s[tid] = ln2w[tid]; b_s[tid] = ln2b[tid]; pb_s[tid] = pb[tid]; }
    __syncthreads();
    // proj + residual -> x2t
    {
        int mt0 = wvi * 16;
        f32x4 acc2[4];
#pragma unroll
        for (int nf = 0; nf < 4; ++nf) acc2[nf] = (f32x4){0.f, 0.f, 0.f, 0.f};
#pragma unroll
        for (int ks = 0; ks < 64; ks += 32) {
            half8v a = *(const half8v*)&q_s[(mt0 + l16) * 72 + ks + quad * 8];
            half8v bfr[4];
#pragma unroll
            for (int nf = 0; nf < 4; ++nf)
                bfr[nf] = *(const half8v*)&s_s[(nf * 16 + l16) * 72 + ks + quad * 8];
#pragma unroll
            for (int nf = 0; nf < 4; ++nf) acc2[nf] = MFMA16(a, bfr[nf], acc2[nf]);
        }
        __syncthreads();
        int tl0 = mt0 + quad * 4;
        int hwl = (h0 + (tl0 >> 3)) * WW + w0 + (tl0 & 7);
#pragma unroll
        for (int nf = 0; nf < 4; ++nf) {
            int j = nf * 16 + l16;
            float bias = pb_s[j];
            float4 rx = *(const float4*)&x[((size_t)(n * CC + j) << 14) + hwl];
#pragma unroll
            for (int r = 0; r < 4; ++r)
                x2t[(tl0 + r) * 68 + j] = acc2[nf][r] + bias + ((const float*)&rx)[r];
        }
    }
    f1b_s[tid] = f1b[tid];
    if (tid < 64) f2b_s[tid] = f2b[tid];
    __syncthreads();
    int tok = tid & 63, cq = tid >> 6;
    {
        float s = 0.f, s2 = 0.f;
#pragma unroll
        for (int e = 0; e < 16; ++e) {
            float f = x2t[tok * 68 + cq * 16 + e];
            s += f; s2 += f * f;
        }
        ps1[tid] = s; ps2[tid] = s2;
    }
    __syncthreads();
    if (tid < 64) {
        float ss = ps1[tid] + ps1[64 + tid] + ps1[128 + tid] + ps1[192 + tid];
        float qq = ps2[tid] + ps2[64 + tid] + ps2[128 + tid] + ps2[192 + tid];
        float m = ss * (1.f / 64.f);
        float var = qq * (1.f / 64.f) - m * m;
        m_s[tid] = m; r_s[tid] = rsqrtf(var + 1e-5f);
    }
    __syncthreads();
    // LN2 -> A2_s (stays in LDS)
    {
        float m = m_s[tok], r = r_s[tok];
        half8v nv0, nv1;
#pragma unroll
        for (int e = 0; e < 8; ++e) {
            int c = cq * 16 + e;
            float f = x2t[tok * 68 + c];
            nv0[e] = (_Float16)((f - m) * r * w_s[c] + b_s[c]);
        }
#pragma unroll
        for (int e = 0; e < 8; ++e) {
            int c = cq * 16 + 8 + e;
            float f = x2t[tok * 68 + c];
            nv1[e] = (_Float16)((f - m) * r * w_s[c] + b_s[c]);
        }
        *(half8v*)&A2_s[tok * 72 + cq * 16] = nv0;
        *(half8v*)&A2_s[tok * 72 + cq * 16 + 8] = nv1;
    }
    __syncthreads();
    // ---- fc1: 4 waves x (64 tok x 64 j); W1 frags f32->f16 from L2 ----
    {
        int nt1 = wvi * 64;
        f32x4 acc[4][4];
#pragma unroll
        for (int mf = 0; mf < 4; ++mf)
#pragma unroll
            for (int nf = 0; nf < 4; ++nf) acc[mf][nf] = (f32x4){0.f, 0.f, 0.f, 0.f};
#pragma unroll
        for (int ks = 0; ks < 64; ks += 32) {
            half8v a[4], bfr[4];
#pragma unroll
            for (int mf = 0; mf < 4; ++mf)
                a[mf] = *(const half8v*)&A2_s[(mf * 16 + l16) * 72 + ks + quad * 8];
#pragma unroll
            for (int nf = 0; nf < 4; ++nf)
                bfr[nf] = cvt8(&f1w[(size_t)(nt1 + nf * 16 + l16) * 64 + ks + quad * 8]);
#pragma unroll
            for (int mf = 0; mf < 4; ++mf)
#pragma unroll
                for (int nf = 0; nf < 4; ++nf) acc[mf][nf] = MFMA16(a[mf], bfr[nf], acc[mf][nf]);
        }
#pragma unroll
        for (int mf = 0; mf < 4; ++mf)
#pragma unroll
            for (int nf = 0; nf < 4; ++nf) {
                int jl = nt1 + nf * 16 + l16;
                float bias = f1b_s[jl];
#pragma unroll
                for (int r = 0; r < 4; ++r) {
                    int tl = mf * 16 + quad * 4 + r;
                    H_s[tl * 264 + jl] = (_Float16)gelu_f(acc[mf][nf][r] + bias);
                }
            }
    }
    __syncthreads();
    // ---- fc2: 4 waves x (16 tok x 64 j), K=256; W2 frags f32->f16 from L2 ----
    {
        int mt = wvi * 16;
        f32x4 acc2[4];
#pragma unroll
        for (int nf = 0; nf < 4; ++nf) acc2[nf] = (f32x4){0.f, 0.f, 0.f, 0.f};
#pragma unroll
        for (int ks = 0; ks < 256; ks += 32) {
            half8v a = *(const half8v*)&H_s[(mt + l16) * 264 + ks + quad * 8];
            half8v bfr[4];
#pragma unroll
            for (int nf = 0; nf < 4; ++nf)
                bfr[nf] = cvt8(&f2w[(size_t)(nf * 16 + l16) * 256 + ks + quad * 8]);
#pragma unroll
            for (int nf = 0; nf < 4; ++nf) acc2[nf] = MFMA16(a, bfr[nf], acc2[nf]);
        }
        __syncthreads();   // all H reads done -> tr overwrite safe
#pragma unroll
        for (int nf = 0; nf < 4; ++nf) {
            int j = nf * 16 + l16;
            float bias = f2b_s[j];
#pragma unroll
            for (int r = 0; r < 4; ++r) {
                int tl = mt + quad * 4 + r;
                float v = acc2[nf][r] + bias + x2t[tl * 68 + j];
                tr_s[j * 68 + tl] = v;
            }
        }
    }
    __syncthreads();
    // ---- NCHW stores ----
    for (int i = tid; i < 2048; i += 256) {
        int j = i >> 5, tl = (i & 31) * 2;
        *(float2*)&out[((size_t)(n * CC + j) << 14)
                       + (size_t)((h0 + (tl >> 3)) * WW + w0 + (tl & 7))] =
            *(const float2*)&tr_s[j * 68 + tl];
    }
}

extern "C" void kernel_launch(void* const* d_in, const int* in_sizes, int n_in,
                              void* d_out, int out_size, void* d_ws, size_t ws_size,
                              hipStream_t stream) {
    const float* x      = (const float*)d_in[0];
    const float* qkv_w  = (const float*)d_in[1];
    const float* qkv_b  = (const float*)d_in[2];
    const float* proj_w = (const float*)d_in[3];
    const float* proj_b = (const float*)d_in[4];
    const float* rpb    = (const float*)d_in[5];
    const float* ln1_w  = (const float*)d_in[6];
    const float* ln1_b  = (const float*)d_in[7];
    const float* ln2_w  = (const float*)d_in[8];
    const float* ln2_b  = (const float*)d_in[9];
    const float* fc1_w  = (const float*)d_in[10];
    const float* fc1_b  = (const float*)d_in[11];
    const float* fc2_w  = (const float*)d_in[12];
    const float* fc2_b  = (const float*)d_in[13];
    float* out = (float*)d_out;
    (void)d_ws; (void)ws_size;

    k_block<<<512, 256, 0, stream>>>(x, qkv_w, qkv_b, proj_w, proj_b, rpb,
                                     ln1_w, ln1_b, ln2_w, ln2_b,
                                     fc1_w, fc1_b, fc2_w, fc2_b, out);
}

// Round 4
// 124.162 us; speedup vs baseline: 1.3907x; 1.3907x over previous
//
#include <hip/hip_runtime.h>
#include <math.h>

#define TQ   32768
#define HWSZ 16384
#define CC   64
#define HH   128
#define WW   128
#define C3   192
#define C4   256
#define KS   7

typedef _Float16 half2v __attribute__((ext_vector_type(2)));
typedef _Float16 half4v __attribute__((ext_vector_type(4)));
typedef _Float16 half8v __attribute__((ext_vector_type(8)));
typedef float    f32x4  __attribute__((ext_vector_type(4)));

#define MFMA16(a, b, c) __builtin_amdgcn_mfma_f32_16x16x32_f16((a), (b), (c), 0, 0, 0)

// gelu tanh-form: max abs dev ~3e-4 vs erf, far under f16 rounding of H.
__device__ __forceinline__ float gelu_f(float v) {
    float z = v * (1.59576912f + 0.07135481f * v * v);
    float e = __expf(-z);
    return v * (1.f / (1.f + e));
}

// ============ K1: LN1 + QKV GEMM + weight-f16 preconvert. grid 256 x 512 thr (8 waves/CU) ====
__global__ __launch_bounds__(512) void k_qkvln(const float* __restrict__ x,
        const float* __restrict__ lnw, const float* __restrict__ lnb,
        const float* __restrict__ qw, const float* __restrict__ qb,
        const float* __restrict__ pw, const float* __restrict__ f1w,
        const float* __restrict__ f2w,
        _Float16* __restrict__ qkv16, _Float16* __restrict__ pw16,
        _Float16* __restrict__ f1w16, _Float16* __restrict__ f2w16) {
    __shared__ union {
        struct { __align__(16) _Float16 A[128 * 72]; __align__(16) _Float16 B[192 * 72]; } st;
        __align__(16) _Float16 outb[128 * 200];
    } u;
    __shared__ float ps1[512], ps2[512], m_s[128], r_s[128];
    __shared__ float w_s[64], b_s[64], bias_s[192];
    int tid = threadIdx.x;
    int t0 = blockIdx.x * 128;
    if (tid < 64) { w_s[tid] = lnw[tid]; b_s[tid] = lnb[tid]; }
    if (tid < 192) bias_s[tid] = qb[tid];
    int tok = tid & 127, cq = tid >> 7;          // cq 0..3, 16 channels each
    int t = t0 + tok;
    int n = t >> 14, hw = t & (HWSZ - 1);
    const float* xr = x + ((size_t)n << 20) + hw;
    float v[16];
    float s = 0.f, s2 = 0.f;
#pragma unroll
    for (int e = 0; e < 16; ++e) {
        float f = xr[(cq * 16 + e) * HWSZ];
        v[e] = f; s += f; s2 += f * f;
    }
    ps1[tid] = s; ps2[tid] = s2;
    for (int i = tid; i < 3072; i += 512) {
        int jj = i >> 4, seg = i & 15;
        float4 v4 = *(const float4*)&qw[(size_t)jj * 64 + seg * 4];
        half4v h4 = { (_Float16)v4.x, (_Float16)v4.y, (_Float16)v4.z, (_Float16)v4.w };
        *(half4v*)&u.st.B[jj * 72 + seg * 4] = h4;
    }
    {
        int g = blockIdx.x * 512 + tid;
        if (g < 4096) pw16[g] = (_Float16)pw[g];
        else if (g < 20480) f1w16[g - 4096] = (_Float16)f1w[g - 4096];
        else if (g < 36864) f2w16[g - 20480] = (_Float16)f2w[g - 20480];
    }
    __syncthreads();
    if (tid < 128) {
        float ss = ps1[tid] + ps1[tid + 128] + ps1[tid + 256] + ps1[tid + 384];
        float qq = ps2[tid] + ps2[tid + 128] + ps2[tid + 256] + ps2[tid + 384];
        float m = ss * (1.f / 64.f);
        float var = qq * (1.f / 64.f) - m * m;
        m_s[tid] = m; r_s[tid] = rsqrtf(var + 1e-5f);
    }
    __syncthreads();
    {
        float m = m_s[tok], r = r_s[tok];
#pragma unroll
        for (int u8 = 0; u8 < 2; ++u8) {
            half8v o;
#pragma unroll
            for (int e = 0; e < 8; ++e) {
                int c = cq * 16 + u8 * 8 + e;
                o[e] = (_Float16)((v[u8 * 8 + e] - m) * r * w_s[c] + b_s[c]);
            }
            *(half8v*)&u.st.A[tok * 72 + cq * 16 + u8 * 8] = o;
        }
    }
    __syncthreads();
    int lane = tid & 63, wv = tid >> 6;          // 8 waves
    int quad = lane >> 4, l16 = lane & 15;
    int mt0 = (wv & 1) * 64, nt0 = (wv >> 1) * 48;
    f32x4 acc[4][3];
#pragma unroll
    for (int mf = 0; mf < 4; ++mf)
#pragma unroll
        for (int nf = 0; nf < 3; ++nf) acc[mf][nf] = (f32x4){0.f, 0.f, 0.f, 0.f};
#pragma unroll
    for (int ks = 0; ks < 64; ks += 32) {
        half8v a[4], bfr[3];
#pragma unroll
        for (int mf = 0; mf < 4; ++mf)
            a[mf] = *(const half8v*)&u.st.A[(mt0 + mf * 16 + l16) * 72 + ks + quad * 8];
#pragma unroll
        for (int nf = 0; nf < 3; ++nf)
            bfr[nf] = *(const half8v*)&u.st.B[(nt0 + nf * 16 + l16) * 72 + ks + quad * 8];
#pragma unroll
        for (int mf = 0; mf < 4; ++mf)
#pragma unroll
            for (int nf = 0; nf < 3; ++nf) acc[mf][nf] = MFMA16(a[mf], bfr[nf], acc[mf][nf]);
    }
    __syncthreads();
    const float qscale = 0.17677669529663687f;
#pragma unroll
    for (int mf = 0; mf < 4; ++mf)
#pragma unroll
        for (int nf = 0; nf < 3; ++nf) {
            int j = nt0 + nf * 16 + l16;
            float bias = bias_s[j];
            float sc = (j < 64) ? qscale : 1.f;
#pragma unroll
            for (int r = 0; r < 4; ++r) {
                int tl = mt0 + mf * 16 + quad * 4 + r;
                u.outb[tl * 200 + j] = (_Float16)((acc[mf][nf][r] + bias) * sc);
            }
        }
    __syncthreads();
    for (int i = tid; i < 4096; i += 512) {
        int tk = i >> 5, rem = i & 31;
        if (rem < 24)
            *(half8v*)&qkv16[(size_t)(t0 + tk) * C3 + rem * 8] =
                *(const half8v*)&u.outb[tk * 200 + rem * 8];
    }
}

// ============ K2: attention + proj + residual + LN2 + MLP fused. grid 512 x 512 thr ==========
// 16 waves/CU (2 blocks x 8 waves); __launch_bounds__(512,4) caps VGPR at 128.
// LDS plan (smem[78216]):
//   attention era: kv_s@0(53312) q_s@53312(10240) s_s@63552(12800) rpb@76352 sum@77704(512)
//   post-attn era: x2t@0(17408) ps1@20480(2048) ps2@22528(2048) m@24576 r@24832 w@25088
//                  b@25344 pb@25600 | A2@53312 f1b@63552 f2b@64576
//   MLP era:       H@17408(33792; overlaps ps/m/r/w/b - all dead)  tr@17408(after H reads)
__global__ __launch_bounds__(512, 4) void k_attn_mlp(const _Float16* __restrict__ qkv16,
        const float* __restrict__ rpb,
        const _Float16* __restrict__ pw16, const float* __restrict__ pb,
        const float* __restrict__ x,
        const float* __restrict__ ln2w, const float* __restrict__ ln2b,
        const _Float16* __restrict__ f1w16, const float* __restrict__ f1b,
        const _Float16* __restrict__ f2w16, const float* __restrict__ f2b,
        float* __restrict__ out) {
    __shared__ __align__(16) char smem[78216];
    _Float16* kv_s  = (_Float16*)smem;
    _Float16* q_s   = (_Float16*)(smem + 53312);
    _Float16* s_s   = (_Float16*)(smem + 63552);
    float*    rpb_s = (float*)(smem + 76352);
    float*    sum_s = (float*)(smem + 77704);
    float* x2t  = (float*)smem;
    float* ps1  = (float*)(smem + 20480);
    float* ps2  = (float*)(smem + 22528);
    float* m_s  = (float*)(smem + 24576);
    float* r_s  = (float*)(smem + 24832);
    float* w_s  = (float*)(smem + 25088);
    float* b_s  = (float*)(smem + 25344);
    float* pb_s = (float*)(smem + 25600);
    _Float16* A2_s = (_Float16*)(smem + 53312);   // xn2 tile, aliases q_s
    _Float16* H_s  = (_Float16*)(smem + 17408);   // fc1 activations
    float*    tr_s = (float*)(smem + 17408);      // transpose staging, after H reads
    float*    f1b_s = (float*)(smem + 63552);
    float*    f2b_s = (float*)(smem + 64576);

    int tid = threadIdx.x;
    int bx = blockIdx.x;
    int n  = bx >> 8;
    int th = (bx >> 4) & 15, tw = bx & 15;
    int h0 = th * 8, w0 = tw * 8;
    int wr0 = min(max(h0 - 3, 0), HH - 14);
    int ww0 = min(max(w0 - 3, 0), WW - 14);
    int tbase = n << 14;
    int lane = tid & 63, wvi = tid >> 6;          // 8 waves
    int quad = lane >> 4, l16 = lane & 15;

    for (int i = tid; i < 338; i += 512) rpb_s[i] = rpb[i];
    for (int i = tid; i < 196 * 16; i += 512) {
        int tk = i >> 4, u = i & 15;
        int wi = tk / 14, wj = tk - wi * 14;
        *(half8v*)&kv_s[tk * 136 + u * 8] = *(const half8v*)&qkv16[
            (size_t)(tbase + (wr0 + wi) * WW + ww0 + wj) * C3 + 64 + u * 8];
    }
    {
        int q8 = tid >> 3, u8 = tid & 7;
        int qg = tbase + (h0 + (q8 >> 3)) * WW + (w0 + (q8 & 7));
        *(half8v*)&q_s[q8 * 80 + u8 * 8] = *(const half8v*)&qkv16[(size_t)qg * C3 + u8 * 8];
    }
    // prefetch proj weights into registers (8KB over 512 thr) — staged to LDS after PV
    half8v pwr = *(const half8v*)&pw16[(size_t)tid * 8];
    __syncthreads();

    int p4 = tid & 3, z = (tid >> 2) & 1, q = tid >> 3;   // q 0..63
    int qy = q >> 3, qx = q & 7;
    int h = h0 + qy, wc = w0 + qx;
    int sh = min(max(h - 3, 0), HH - KS);
    int sw = min(max(wc - 3, 0), WW - KS);
    int oh = sh - wr0, ow = sw - ww0;
    int dhp = h - sh + 6, dwp = wc - sw + 6;
    // ---- QK^T + bias: 4 threads per (q,z) row at nb stride 4 ----
    {
        const half8v* qp = (const half8v*)&q_s[q * 80 + z * 32];
        half8v q0 = qp[0], q1 = qp[1], q2 = qp[2], q3 = qp[3];
        int i7 = 0, j7 = p4;
        for (int nb = p4; nb < 49; nb += 4) {
            int tk = (oh + i7) * 14 + (ow + j7);
            const half8v* kp = (const half8v*)&kv_s[tk * 136 + z * 32];
            half2v acc2 = { (_Float16)0.f, (_Float16)0.f };
            half8v k0 = kp[0], k1 = kp[1], k2 = kp[2], k3 = kp[3];
            acc2 += (half2v){k0.s0, k0.s1} * (half2v){q0.s0, q0.s1};
            acc2 += (half2v){k0.s2, k0.s3} * (half2v){q0.s2, q0.s3};
            acc2 += (half2v){k0.s4, k0.s5} * (half2v){q0.s4, q0.s5};
            acc2 += (half2v){k0.s6, k0.s7} * (half2v){q0.s6, q0.s7};
            acc2 += (half2v){k1.s0, k1.s1} * (half2v){q1.s0, q1.s1};
            acc2 += (half2v){k1.s2, k1.s3} * (half2v){q1.s2, q1.s3};
            acc2 += (half2v){k1.s4, k1.s5} * (half2v){q1.s4, q1.s5};
            acc2 += (half2v){k1.s6, k1.s7} * (half2v){q1.s6, q1.s7};
            acc2 += (half2v){k2.s0, k2.s1} * (half2v){q2.s0, q2.s1};
            acc2 += (half2v){k2.s2, k2.s3} * (half2v){q2.s2, q2.s3};
            acc2 += (half2v){k2.s4, k2.s5} * (half2v){q2.s4, q2.s5};
            acc2 += (half2v){k2.s6, k2.s7} * (half2v){q2.s6, q2.s7};
            acc2 += (half2v){k3.s0, k3.s1} * (half2v){q3.s0, q3.s1};
            acc2 += (half2v){k3.s2, k3.s3} * (half2v){q3.s2, q3.s3};
            acc2 += (half2v){k3.s4, k3.s5} * (half2v){q3.s4, q3.s5};
            acc2 += (half2v){k3.s6, k3.s7} * (half2v){q3.s6, q3.s7};
            float s = (float)acc2.x + (float)acc2.y
                    + rpb_s[(z * 13 + (dhp - i7)) * 13 + (dwp - j7)];
            s_s[(q * 2 + z) * 50 + nb] = (_Float16)s;
            j7 += 4;
            if (j7 >= 7) { j7 -= 7; ++i7; }
        }
    }
    __syncthreads();

    // ---- softmax: 4 threads/row (512 thr, 128 rows); unnormalized exp, 1/sum deferred ----
    {
        int row = tid >> 2, h4 = tid & 3;
        _Float16* sp = &s_s[row * 50];
        float mx = -1e30f;
        for (int i = h4; i < 49; i += 4) mx = fmaxf(mx, (float)sp[i]);
        mx = fmaxf(mx, __shfl_xor(mx, 1));
        mx = fmaxf(mx, __shfl_xor(mx, 2));
        float sum = 0.f;
        for (int i = h4; i < 49; i += 4) {
            float e = __expf((float)sp[i] - mx);
            sum += e;
            sp[i] = (_Float16)e;
        }
        sum += __shfl_xor(sum, 1);
        sum += __shfl_xor(sum, 2);
        if (h4 == 0) sum_s[row] = 1.f / sum;
    }
    __syncthreads();

    // ---- PV: 4 threads per (q,z) row, 8 channels each ----
    {
        int c8 = tid & 3;
        const _Float16* pp = &s_s[(q * 2 + z) * 50];
        half2v acc[4];
#pragma unroll
        for (int j = 0; j < 4; ++j) acc[j] = (half2v){ (_Float16)0.f, (_Float16)0.f };
        int i7 = 0, j7 = 0;
        for (int nb = 0; nb < 49; ++nb) {
            int tk = (oh + i7) * 14 + (ow + j7);
            _Float16 p = pp[nb];
            half2v p2 = { p, p };
            half8v v0 = *(const half8v*)&kv_s[tk * 136 + 64 + z * 32 + c8 * 8];
            acc[0] += (half2v){v0.s0, v0.s1} * p2;
            acc[1] += (half2v){v0.s2, v0.s3} * p2;
            acc[2] += (half2v){v0.s4, v0.s5} * p2;
            acc[3] += (half2v){v0.s6, v0.s7} * p2;
            ++j7;
            if (j7 == 7) { j7 = 0; ++i7; }
        }
        float inv = sum_s[q * 2 + z];
        half8v o0;
#pragma unroll
        for (int j = 0; j < 4; ++j) {
            o0[2 * j]     = (_Float16)((float)acc[j].x * inv);
            o0[2 * j + 1] = (_Float16)((float)acc[j].y * inv);
        }
        *(half8v*)(q_s + q * 72 + z * 32 + c8 * 8) = o0;
    }
    __syncthreads();
    // proj weights: LDS write from prefetched regs
    *(half8v*)&s_s[(tid >> 3) * 72 + (tid & 7) * 8] = pwr;
    if (tid < 64) { w_s[tid] = ln2w[tid]; b_s[tid] = ln2b[tid]; pb_s[tid] = pb[tid]; }
    __syncthreads();
    // ---- proj + residual -> x2t: 8 waves x (16 tok x 32 j) ----
    {
        int mt0 = (wvi & 3) * 16, n0 = (wvi >> 2) * 32;
        f32x4 acc2[2];
#pragma unroll
        for (int nf = 0; nf < 2; ++nf) acc2[nf] = (f32x4){0.f, 0.f, 0.f, 0.f};
#pragma unroll
        for (int ks = 0; ks < 64; ks += 32) {
            half8v a = *(const half8v*)&q_s[(mt0 + l16) * 72 + ks + quad * 8];
            half8v bfr[2];
#pragma unroll
            for (int nf = 0; nf < 2; ++nf)
                bfr[nf] = *(const half8v*)&s_s[(n0 + nf * 16 + l16) * 72 + ks + quad * 8];
#pragma unroll
            for (int nf = 0; nf < 2; ++nf) acc2[nf] = MFMA16(a, bfr[nf], acc2[nf]);
        }
        __syncthreads();
        int tl0 = mt0 + quad * 4;
        int hwl = (h0 + (tl0 >> 3)) * WW + w0 + (tl0 & 7);
#pragma unroll
        for (int nf = 0; nf < 2; ++nf) {
            int j = n0 + nf * 16 + l16;
            float bias = pb_s[j];
            float4 rx = *(const float4*)&x[((size_t)(n * CC + j) << 14) + hwl];
#pragma unroll
            for (int r = 0; r < 2; ++r);
#pragma unroll
            for (int r = 0; r < 4; ++r)
                x2t[(tl0 + r) * 68 + j] = acc2[nf][r] + bias + ((const float*)&rx)[r];
        }
    }
    if (tid < 256) f1b_s[tid] = f1b[tid];
    else if (tid < 320) f2b_s[tid - 256] = f2b[tid - 256];
    __syncthreads();
    int tok = tid & 63, cq = tid >> 6;            // cq 0..7, 8 channels each
    {
        float s = 0.f, s2 = 0.f;
#pragma unroll
        for (int e = 0; e < 8; ++e) {
            float f = x2t[tok * 68 + cq * 8 + e];
            s += f; s2 += f * f;
        }
        ps1[tid] = s; ps2[tid] = s2;
    }
    __syncthreads();
    if (tid < 64) {
        float ss = 0.f, qq = 0.f;
#pragma unroll
        for (int k = 0; k < 8; ++k) { ss += ps1[tid + 64 * k]; qq += ps2[tid + 64 * k]; }
        float m = ss * (1.f / 64.f);
        float var = qq * (1.f / 64.f) - m * m;
        m_s[tid] = m; r_s[tid] = rsqrtf(var + 1e-5f);
    }
    __syncthreads();
    // LN2 -> A2_s (stays in LDS)
    {
        float m = m_s[tok], r = r_s[tok];
        half8v nv0;
#pragma unroll
        for (int e = 0; e < 8; ++e) {
            int c = cq * 8 + e;
            float f = x2t[tok * 68 + c];
            nv0[e] = (_Float16)((f - m) * r * w_s[c] + b_s[c]);
        }
        *(half8v*)&A2_s[tok * 72 + cq * 8] = nv0;
    }
    __syncthreads();   // A2 ready; x2t/w/b consumed before H clobbers
    // ---- fc1: 8 waves x (32 tok x 64 j); W1 f16 from L2 ----
    {
        int mt0 = (wvi & 1) * 32, nt1 = (wvi >> 1) * 64;
        f32x4 acc[2][4];
#pragma unroll
        for (int mf = 0; mf < 2; ++mf)
#pragma unroll
            for (int nf = 0; nf < 4; ++nf) acc[mf][nf] = (f32x4){0.f, 0.f, 0.f, 0.f};
#pragma unroll
        for (int ks = 0; ks < 64; ks += 32) {
            half8v a[2], bfr[4];
#pragma unroll
            for (int mf = 0; mf < 2; ++mf)
                a[mf] = *(const half8v*)&A2_s[(mt0 + mf * 16 + l16) * 72 + ks + quad * 8];
#pragma unroll
            for (int nf = 0; nf < 4; ++nf)
                bfr[nf] = *(const half8v*)&f1w16[(size_t)(nt1 + nf * 16 + l16) * 64 + ks + quad * 8];
#pragma unroll
            for (int mf = 0; mf < 2; ++mf)
#pragma unroll
                for (int nf = 0; nf < 4; ++nf) acc[mf][nf] = MFMA16(a[mf], bfr[nf], acc[mf][nf]);
        }
#pragma unroll
        for (int mf = 0; mf < 2; ++mf)
#pragma unroll
            for (int nf = 0; nf < 4; ++nf) {
                int jl = nt1 + nf * 16 + l16;
                float bias = f1b_s[jl];
#pragma unroll
                for (int r = 0; r < 4; ++r) {
                    int tl = mt0 + mf * 16 + quad * 4 + r;
                    H_s[tl * 264 + jl] = (_Float16)gelu_f(acc[mf][nf][r] + bias);
                }
            }
    }
    __syncthreads();   // H complete
    // ---- fc2: 8 waves x (16 tok x 32 j), K=256; W2 f16 from L2 ----
    {
        int mt = (wvi & 3) * 16, n0 = (wvi >> 2) * 32;
        f32x4 acc2[2];
#pragma unroll
        for (int nf = 0; nf < 2; ++nf) acc2[nf] = (f32x4){0.f, 0.f, 0.f, 0.f};
#pragma unroll
        for (int ks = 0; ks < 256; ks += 32) {
            half8v a = *(const half8v*)&H_s[(mt + l16) * 264 + ks + quad * 8];
            half8v bfr[2];
#pragma unroll
            for (int nf = 0; nf < 2; ++nf)
                bfr[nf] = *(const half8v*)&f2w16[(size_t)(n0 + nf * 16 + l16) * 256 + ks + quad * 8];
#pragma unroll
            for (int nf = 0; nf < 2; ++nf) acc2[nf] = MFMA16(a, bfr[nf], acc2[nf]);
        }
        __syncthreads();   // all H reads done -> tr overwrite safe
#pragma unroll
        for (int nf = 0; nf < 2; ++nf) {
            int j = n0 + nf * 16 + l16;
            float bias = f2b_s[j];
#pragma unroll
            for (int r = 0; r < 4; ++r) {
                int tl = mt + quad * 4 + r;
                float v = acc2[nf][r] + bias + x2t[tl * 68 + j];
                tr_s[j * 68 + tl] = v;
            }
        }
    }
    __syncthreads();   // tr complete
    // ---- NCHW stores ----
    for (int i = tid; i < 2048; i += 512) {
        int j = i >> 5, tl = (i & 31) * 2;
        *(float2*)&out[((size_t)(n * CC + j) << 14)
                       + (size_t)((h0 + (tl >> 3)) * WW + w0 + (tl & 7))] =
            *(const float2*)&tr_s[j * 68 + tl];
    }
}

extern "C" void kernel_launch(void* const* d_in, const int* in_sizes, int n_in,
                              void* d_out, int out_size, void* d_ws, size_t ws_size,
                              hipStream_t stream) {
    const float* x      = (const float*)d_in[0];
    const float* qkv_w  = (const float*)d_in[1];
    const float* qkv_b  = (const float*)d_in[2];
    const float* proj_w = (const float*)d_in[3];
    const float* proj_b = (const float*)d_in[4];
    const float* rpb    = (const float*)d_in[5];
    const float* ln1_w  = (const float*)d_in[6];
    const float* ln1_b  = (const float*)d_in[7];
    const float* ln2_w  = (const float*)d_in[8];
    const float* ln2_b  = (const float*)d_in[9];
    const float* fc1_w  = (const float*)d_in[10];
    const float* fc1_b  = (const float*)d_in[11];
    const float* fc2_w  = (const float*)d_in[12];
    const float* fc2_b  = (const float*)d_in[13];
    float* out = (float*)d_out;
    char* ws = (char*)d_ws;

    _Float16* qkv16  = (_Float16*)(ws);                 // 12.58 MB [T][192]
    _Float16* pw16   = (_Float16*)(ws + 20971520);      //  8 KB
    _Float16* f1w16  = (_Float16*)(ws + 20979712);      // 32 KB
    _Float16* f2w16  = (_Float16*)(ws + 21012480);      // 32 KB

    k_qkvln   <<<256, 512, 0, stream>>>(x, ln1_w, ln1_b, qkv_w, qkv_b,
                                        proj_w, fc1_w, fc2_w,
                                        qkv16, pw16, f1w16, f2w16);
    k_attn_mlp<<<512, 512, 0, stream>>>(qkv16, rpb, pw16, proj_b, x, ln2_w, ln2_b,
                                        f1w16, fc1_b, f2w16, fc2_b, out);
}

// Round 5
// 123.906 us; speedup vs baseline: 1.3936x; 1.0021x over previous
//
#include <hip/hip_runtime.h>
#include <math.h>

#define TQ   32768
#define HWSZ 16384
#define CC   64
#define HH   128
#define WW   128
#define C3   192
#define C4   256
#define KS   7

typedef _Float16 half2v __attribute__((ext_vector_type(2)));
typedef _Float16 half4v __attribute__((ext_vector_type(4)));
typedef _Float16 half8v __attribute__((ext_vector_type(8)));
typedef float    f32x4  __attribute__((ext_vector_type(4)));

#define MFMA16(a, b, c) __builtin_amdgcn_mfma_f32_16x16x32_f16((a), (b), (c), 0, 0, 0)

// gelu tanh-form: max abs dev ~3e-4 vs erf, far under f16 rounding of H.
__device__ __forceinline__ float gelu_f(float v) {
    float z = v * (1.59576912f + 0.07135481f * v * v);
    float e = __expf(-z);
    return v * (1.f / (1.f + e));
}

// ============ K1: LN1 + QKV GEMM + weight-f16 preconvert. grid 256 x 512 thr ============
__global__ __launch_bounds__(512) void k_qkvln(const float* __restrict__ x,
        const float* __restrict__ lnw, const float* __restrict__ lnb,
        const float* __restrict__ qw, const float* __restrict__ qb,
        const float* __restrict__ pw, const float* __restrict__ f1w,
        const float* __restrict__ f2w,
        _Float16* __restrict__ qkv16, _Float16* __restrict__ pw16,
        _Float16* __restrict__ f1w16, _Float16* __restrict__ f2w16) {
    __shared__ union {
        struct { __align__(16) _Float16 A[128 * 72]; __align__(16) _Float16 B[192 * 72]; } st;
        __align__(16) _Float16 outb[128 * 200];
    } u;
    __shared__ float ps1[512], ps2[512], m_s[128], r_s[128];
    __shared__ float w_s[64], b_s[64], bias_s[192];
    int tid = threadIdx.x;
    int t0 = blockIdx.x * 128;
    if (tid < 64) { w_s[tid] = lnw[tid]; b_s[tid] = lnb[tid]; }
    if (tid < 192) bias_s[tid] = qb[tid];
    int tok = tid & 127, cq = tid >> 7;          // cq 0..3, 16 channels each
    int t = t0 + tok;
    int n = t >> 14, hw = t & (HWSZ - 1);
    const float* xr = x + ((size_t)n << 20) + hw;
    float v[16];
    float s = 0.f, s2 = 0.f;
#pragma unroll
    for (int e = 0; e < 16; ++e) {
        float f = xr[(cq * 16 + e) * HWSZ];
        v[e] = f; s += f; s2 += f * f;
    }
    ps1[tid] = s; ps2[tid] = s2;
    for (int i = tid; i < 3072; i += 512) {
        int jj = i >> 4, seg = i & 15;
        float4 v4 = *(const float4*)&qw[(size_t)jj * 64 + seg * 4];
        half4v h4 = { (_Float16)v4.x, (_Float16)v4.y, (_Float16)v4.z, (_Float16)v4.w };
        *(half4v*)&u.st.B[jj * 72 + seg * 4] = h4;
    }
    {
        int g = blockIdx.x * 512 + tid;
        if (g < 4096) pw16[g] = (_Float16)pw[g];
        else if (g < 20480) f1w16[g - 4096] = (_Float16)f1w[g - 4096];
        else if (g < 36864) f2w16[g - 20480] = (_Float16)f2w[g - 20480];
    }
    __syncthreads();
    if (tid < 128) {
        float ss = ps1[tid] + ps1[tid + 128] + ps1[tid + 256] + ps1[tid + 384];
        float qq = ps2[tid] + ps2[tid + 128] + ps2[tid + 256] + ps2[tid + 384];
        float m = ss * (1.f / 64.f);
        float var = qq * (1.f / 64.f) - m * m;
        m_s[tid] = m; r_s[tid] = rsqrtf(var + 1e-5f);
    }
    __syncthreads();
    {
        float m = m_s[tok], r = r_s[tok];
#pragma unroll
        for (int u8 = 0; u8 < 2; ++u8) {
            half8v o;
#pragma unroll
            for (int e = 0; e < 8; ++e) {
                int c = cq * 16 + u8 * 8 + e;
                o[e] = (_Float16)((v[u8 * 8 + e] - m) * r * w_s[c] + b_s[c]);
            }
            *(half8v*)&u.st.A[tok * 72 + cq * 16 + u8 * 8] = o;
        }
    }
    __syncthreads();
    int lane = tid & 63, wv = tid >> 6;          // 8 waves
    int quad = lane >> 4, l16 = lane & 15;
    int mt0 = (wv & 1) * 64, nt0 = (wv >> 1) * 48;
    f32x4 acc[4][3];
#pragma unroll
    for (int mf = 0; mf < 4; ++mf)
#pragma unroll
        for (int nf = 0; nf < 3; ++nf) acc[mf][nf] = (f32x4){0.f, 0.f, 0.f, 0.f};
#pragma unroll
    for (int ks = 0; ks < 64; ks += 32) {
        half8v a[4], bfr[3];
#pragma unroll
        for (int mf = 0; mf < 4; ++mf)
            a[mf] = *(const half8v*)&u.st.A[(mt0 + mf * 16 + l16) * 72 + ks + quad * 8];
#pragma unroll
        for (int nf = 0; nf < 3; ++nf)
            bfr[nf] = *(const half8v*)&u.st.B[(nt0 + nf * 16 + l16) * 72 + ks + quad * 8];
#pragma unroll
        for (int mf = 0; mf < 4; ++mf)
#pragma unroll
            for (int nf = 0; nf < 3; ++nf) acc[mf][nf] = MFMA16(a[mf], bfr[nf], acc[mf][nf]);
    }
    __syncthreads();
    const float qscale = 0.17677669529663687f;
#pragma unroll
    for (int mf = 0; mf < 4; ++mf)
#pragma unroll
        for (int nf = 0; nf < 3; ++nf) {
            int j = nt0 + nf * 16 + l16;
            float bias = bias_s[j];
            float sc = (j < 64) ? qscale : 1.f;
#pragma unroll
            for (int r = 0; r < 4; ++r) {
                int tl = mt0 + mf * 16 + quad * 4 + r;
                u.outb[tl * 200 + j] = (_Float16)((acc[mf][nf][r] + bias) * sc);
            }
        }
    __syncthreads();
    for (int i = tid; i < 4096; i += 512) {
        int tk = i >> 5, rem = i & 31;
        if (rem < 24)
            *(half8v*)&qkv16[(size_t)(t0 + tk) * C3 + rem * 8] =
                *(const half8v*)&u.outb[tk * 200 + rem * 8];
    }
}

// ============ K2: attention (barrier-free, reg+shfl) + proj + residual + LN2 + MLP ==========
// grid 512 x 512 thr; __launch_bounds__(512,4) caps VGPR at 128 -> 2 blocks/CU.
// LDS plan (smem[78216]):
//   attention era: kv_s@0(53312) q_s@53312(10240) rpb@76352   (NO score LDS: regs + shfl)
//   post-attn era: x2t@0(17408) ps1@20480(2048) ps2@22528(2048) m@24576 r@24832 w@25088
//                  b@25344 pb@25600 | pw-stage s_s@63552 | A2@53312 f1b@63552 f2b@64576
//   MLP era:       H@17408(33792)  tr@17408(after H reads)
__global__ __launch_bounds__(512, 4) void k_attn_mlp(const _Float16* __restrict__ qkv16,
        const float* __restrict__ rpb,
        const _Float16* __restrict__ pw16, const float* __restrict__ pb,
        const float* __restrict__ x,
        const float* __restrict__ ln2w, const float* __restrict__ ln2b,
        const _Float16* __restrict__ f1w16, const float* __restrict__ f1b,
        const _Float16* __restrict__ f2w16, const float* __restrict__ f2b,
        float* __restrict__ out) {
    __shared__ __align__(16) char smem[78216];
    _Float16* kv_s  = (_Float16*)smem;
    _Float16* q_s   = (_Float16*)(smem + 53312);
    _Float16* s_s   = (_Float16*)(smem + 63552);  // pw stage (post-PV era only)
    float*    rpb_s = (float*)(smem + 76352);
    float* x2t  = (float*)smem;
    float* ps1  = (float*)(smem + 20480);
    float* ps2  = (float*)(smem + 22528);
    float* m_s  = (float*)(smem + 24576);
    float* r_s  = (float*)(smem + 24832);
    float* w_s  = (float*)(smem + 25088);
    float* b_s  = (float*)(smem + 25344);
    float* pb_s = (float*)(smem + 25600);
    _Float16* A2_s = (_Float16*)(smem + 53312);   // xn2 tile, aliases q_s
    _Float16* H_s  = (_Float16*)(smem + 17408);   // fc1 activations
    float*    tr_s = (float*)(smem + 17408);      // transpose staging, after H reads
    float*    f1b_s = (float*)(smem + 63552);
    float*    f2b_s = (float*)(smem + 64576);

    int tid = threadIdx.x;
    int bx = blockIdx.x;
    int n  = bx >> 8;
    int th = (bx >> 4) & 15, tw = bx & 15;
    int h0 = th * 8, w0 = tw * 8;
    int wr0 = min(max(h0 - 3, 0), HH - 14);
    int ww0 = min(max(w0 - 3, 0), WW - 14);
    int tbase = n << 14;
    int lane = tid & 63, wvi = tid >> 6;          // 8 waves
    int quad = lane >> 4, l16 = lane & 15;

    for (int i = tid; i < 338; i += 512) rpb_s[i] = rpb[i];
    for (int i = tid; i < 196 * 16; i += 512) {
        int tk = i >> 4, u = i & 15;
        int wi = tk / 14, wj = tk - wi * 14;
        *(half8v*)&kv_s[tk * 136 + u * 8] = *(const half8v*)&qkv16[
            (size_t)(tbase + (wr0 + wi) * WW + ww0 + wj) * C3 + 64 + u * 8];
    }
    {
        int q8 = tid >> 3, u8 = tid & 7;
        int qg = tbase + (h0 + (q8 >> 3)) * WW + (w0 + (q8 & 7));
        *(half8v*)&q_s[q8 * 80 + u8 * 8] = *(const half8v*)&qkv16[(size_t)qg * C3 + u8 * 8];
    }
    // prefetch proj weights into registers (8KB over 512 thr) — staged to LDS after PV
    half8v pwr = *(const half8v*)&pw16[(size_t)tid * 8];
    __syncthreads();

    int p4 = tid & 3, z = (tid >> 2) & 1, q = tid >> 3;   // q 0..63; group of 4 lanes = 1 row
    int qy = q >> 3, qx = q & 7;
    int h = h0 + qy, wc = w0 + qx;
    int sh = min(max(h - 3, 0), HH - KS);
    int sw = min(max(wc - 3, 0), WW - KS);
    int oh = sh - wr0, ow = sw - ww0;
    int dhp = h - sh + 6, dwp = wc - sw + 6;

    // ---- QK^T + bias -> registers (13 scores/thread); no LDS, no barrier ----
    float ereg[13];
    float inv;
    {
        const half8v* qp = (const half8v*)&q_s[q * 80 + z * 32];
        half8v q0 = qp[0], q1 = qp[1], q2 = qp[2], q3 = qp[3];
        float mx = -1e30f;
        int i7 = 0, j7 = p4;
#pragma unroll
        for (int k = 0; k < 13; ++k) {
            int nb = p4 + 4 * k;
            if (nb < 49) {
                int tk = (oh + i7) * 14 + (ow + j7);
                const half8v* kp = (const half8v*)&kv_s[tk * 136 + z * 32];
                half2v acc2 = { (_Float16)0.f, (_Float16)0.f };
                half8v k0 = kp[0], k1 = kp[1], k2 = kp[2], k3 = kp[3];
                acc2 += (half2v){k0.s0, k0.s1} * (half2v){q0.s0, q0.s1};
                acc2 += (half2v){k0.s2, k0.s3} * (half2v){q0.s2, q0.s3};
                acc2 += (half2v){k0.s4, k0.s5} * (half2v){q0.s4, q0.s5};
                acc2 += (half2v){k0.s6, k0.s7} * (half2v){q0.s6, q0.s7};
                acc2 += (half2v){k1.s0, k1.s1} * (half2v){q1.s0, q1.s1};
                acc2 += (half2v){k1.s2, k1.s3} * (half2v){q1.s2, q1.s3};
                acc2 += (half2v){k1.s4, k1.s5} * (half2v){q1.s4, q1.s5};
                acc2 += (half2v){k1.s6, k1.s7} * (half2v){q1.s6, q1.s7};
                acc2 += (half2v){k2.s0, k2.s1} * (half2v){q2.s0, q2.s1};
                acc2 += (half2v){k2.s2, k2.s3} * (half2v){q2.s2, q2.s3};
                acc2 += (half2v){k2.s4, k2.s5} * (half2v){q2.s4, q2.s5};
                acc2 += (half2v){k2.s6, k2.s7} * (half2v){q2.s6, q2.s7};
                acc2 += (half2v){k3.s0, k3.s1} * (half2v){q3.s0, q3.s1};
                acc2 += (half2v){k3.s2, k3.s3} * (half2v){q3.s2, q3.s3};
                acc2 += (half2v){k3.s4, k3.s5} * (half2v){q3.s4, q3.s5};
                acc2 += (half2v){k3.s6, k3.s7} * (half2v){q3.s6, q3.s7};
                ereg[k] = (float)acc2.x + (float)acc2.y
                        + rpb_s[(z * 13 + (dhp - i7)) * 13 + (dwp - j7)];
                mx = fmaxf(mx, ereg[k]);
                j7 += 4;
                if (j7 >= 7) { j7 -= 7; ++i7; }
            } else {
                ereg[k] = -1e30f;
            }
        }
        // row max across the 4-lane group
        mx = fmaxf(mx, __shfl_xor(mx, 1));
        mx = fmaxf(mx, __shfl_xor(mx, 2));
        float sum = 0.f;
#pragma unroll
        for (int k = 0; k < 13; ++k) {
            int nb = p4 + 4 * k;
            if (nb < 49) {
                float e = __expf(ereg[k] - mx);
                ereg[k] = e;
                sum += e;
            }
        }
        sum += __shfl_xor(sum, 1);
        sum += __shfl_xor(sum, 2);
        inv = 1.f / sum;
    }

    // ---- PV: p broadcast via width-4 shfl; 8 channels/thread; no barrier ----
    {
        int c8 = p4;
        half2v acc[4];
#pragma unroll
        for (int j = 0; j < 4; ++j) acc[j] = (half2v){ (_Float16)0.f, (_Float16)0.f };
#pragma unroll
        for (int nb = 0; nb < 49; ++nb) {
            float pf = __shfl(ereg[nb >> 2], nb & 3, 4);
            int tk = (oh + nb / 7) * 14 + (ow + nb % 7);
            _Float16 p = (_Float16)pf;
            half2v p2 = { p, p };
            half8v v0 = *(const half8v*)&kv_s[tk * 136 + 64 + z * 32 + c8 * 8];
            acc[0] += (half2v){v0.s0, v0.s1} * p2;
            acc[1] += (half2v){v0.s2, v0.s3} * p2;
            acc[2] += (half2v){v0.s4, v0.s5} * p2;
            acc[3] += (half2v){v0.s6, v0.s7} * p2;
        }
        half8v o0;
#pragma unroll
        for (int j = 0; j < 4; ++j) {
            o0[2 * j]     = (_Float16)((float)acc[j].x * inv);
            o0[2 * j + 1] = (_Float16)((float)acc[j].y * inv);
        }
        *(half8v*)(q_s + q * 72 + z * 32 + c8 * 8) = o0;
    }
    __syncthreads();
    // proj weights: LDS write from prefetched regs
    *(half8v*)&s_s[(tid >> 3) * 72 + (tid & 7) * 8] = pwr;
    if (tid < 64) { w_s[tid] = ln2w[tid]; b_s[tid] = ln2b[tid]; pb_s[tid] = pb[tid]; }
    __syncthreads();
    // ---- proj + residual -> x2t: 8 waves x (16 tok x 32 j) ----
    {
        int mt0 = (wvi & 3) * 16, n0 = (wvi >> 2) * 32;
        f32x4 acc2[2];
#pragma unroll
        for (int nf = 0; nf < 2; ++nf) acc2[nf] = (f32x4){0.f, 0.f, 0.f, 0.f};
#pragma unroll
        for (int ks = 0; ks < 64; ks += 32) {
            half8v a = *(const half8v*)&q_s[(mt0 + l16) * 72 + ks + quad * 8];
            half8v bfr[2];
#pragma unroll
            for (int nf = 0; nf < 2; ++nf)
                bfr[nf] = *(const half8v*)&s_s[(n0 + nf * 16 + l16) * 72 + ks + quad * 8];
#pragma unroll
            for (int nf = 0; nf < 2; ++nf) acc2[nf] = MFMA16(a, bfr[nf], acc2[nf]);
        }
        __syncthreads();
        int tl0 = mt0 + quad * 4;
        int hwl = (h0 + (tl0 >> 3)) * WW + w0 + (tl0 & 7);
#pragma unroll
        for (int nf = 0; nf < 2; ++nf) {
            int j = n0 + nf * 16 + l16;
            float bias = pb_s[j];
            float4 rx = *(const float4*)&x[((size_t)(n * CC + j) << 14) + hwl];
#pragma unroll
            for (int r = 0; r < 4; ++r)
                x2t[(tl0 + r) * 68 + j] = acc2[nf][r] + bias + ((const float*)&rx)[r];
        }
    }
    if (tid < 256) f1b_s[tid] = f1b[tid];
    else if (tid < 320) f2b_s[tid - 256] = f2b[tid - 256];
    __syncthreads();
    int tok = tid & 63, cq = tid >> 6;            // cq 0..7, 8 channels each
    {
        float s = 0.f, s2 = 0.f;
#pragma unroll
        for (int e = 0; e < 8; ++e) {
            float f = x2t[tok * 68 + cq * 8 + e];
            s += f; s2 += f * f;
        }
        ps1[tid] = s; ps2[tid] = s2;
    }
    __syncthreads();
    if (tid < 64) {
        float ss = 0.f, qq = 0.f;
#pragma unroll
        for (int k = 0; k < 8; ++k) { ss += ps1[tid + 64 * k]; qq += ps2[tid + 64 * k]; }
        float m = ss * (1.f / 64.f);
        float var = qq * (1.f / 64.f) - m * m;
        m_s[tid] = m; r_s[tid] = rsqrtf(var + 1e-5f);
    }
    __syncthreads();
    // LN2 -> A2_s (stays in LDS)
    {
        float m = m_s[tok], r = r_s[tok];
        half8v nv0;
#pragma unroll
        for (int e = 0; e < 8; ++e) {
            int c = cq * 8 + e;
            float f = x2t[tok * 68 + c];
            nv0[e] = (_Float16)((f - m) * r * w_s[c] + b_s[c]);
        }
        *(half8v*)&A2_s[tok * 72 + cq * 8] = nv0;
    }
    __syncthreads();   // A2 ready; x2t/w/b consumed before H clobbers
    // ---- fc1: 8 waves x (32 tok x 64 j); W1 f16 from L2 ----
    {
        int mt0 = (wvi & 1) * 32, nt1 = (wvi >> 1) * 64;
        f32x4 acc[2][4];
#pragma unroll
        for (int mf = 0; mf < 2; ++mf)
#pragma unroll
            for (int nf = 0; nf < 4; ++nf) acc[mf][nf] = (f32x4){0.f, 0.f, 0.f, 0.f};
#pragma unroll
        for (int ks = 0; ks < 64; ks += 32) {
            half8v a[2], bfr[4];
#pragma unroll
            for (int mf = 0; mf < 2; ++mf)
                a[mf] = *(const half8v*)&A2_s[(mt0 + mf * 16 + l16) * 72 + ks + quad * 8];
#pragma unroll
            for (int nf = 0; nf < 4; ++nf)
                bfr[nf] = *(const half8v*)&f1w16[(size_t)(nt1 + nf * 16 + l16) * 64 + ks + quad * 8];
#pragma unroll
            for (int mf = 0; mf < 2; ++mf)
#pragma unroll
                for (int nf = 0; nf < 4; ++nf) acc[mf][nf] = MFMA16(a[mf], bfr[nf], acc[mf][nf]);
        }
#pragma unroll
        for (int mf = 0; mf < 2; ++mf)
#pragma unroll
            for (int nf = 0; nf < 4; ++nf) {
                int jl = nt1 + nf * 16 + l16;
                float bias = f1b_s[jl];
#pragma unroll
                for (int r = 0; r < 4; ++r) {
                    int tl = mt0 + mf * 16 + quad * 4 + r;
                    H_s[tl * 264 + jl] = (_Float16)gelu_f(acc[mf][nf][r] + bias);
                }
            }
    }
    __syncthreads();   // H complete
    // ---- fc2: 8 waves x (16 tok x 32 j), K=256; W2 f16 from L2 ----
    {
        int mt = (wvi & 3) * 16, n0 = (wvi >> 2) * 32;
        f32x4 acc2[2];
#pragma unroll
        for (int nf = 0; nf < 2; ++nf) acc2[nf] = (f32x4){0.f, 0.f, 0.f, 0.f};
#pragma unroll
        for (int ks = 0; ks < 256; ks += 32) {
            half8v a = *(const half8v*)&H_s[(mt + l16) * 264 + ks + quad * 8];
            half8v bfr[2];
#pragma unroll
            for (int nf = 0; nf < 2; ++nf)
                bfr[nf] = *(const half8v*)&f2w16[(size_t)(n0 + nf * 16 + l16) * 256 + ks + quad * 8];
#pragma unroll
            for (int nf = 0; nf < 2; ++nf) acc2[nf] = MFMA16(a, bfr[nf], acc2[nf]);
        }
        __syncthreads();   // all H reads done -> tr overwrite safe
#pragma unroll
        for (int nf = 0; nf < 2; ++nf) {
            int j = n0 + nf * 16 + l16;
            float bias = f2b_s[j];
#pragma unroll
            for (int r = 0; r < 4; ++r) {
                int tl = mt + quad * 4 + r;
                float v = acc2[nf][r] + bias + x2t[tl * 68 + j];
                tr_s[j * 68 + tl] = v;
            }
        }
    }
    __syncthreads();   // tr complete
    // ---- NCHW stores ----
    for (int i = tid; i < 2048; i += 512) {
        int j = i >> 5, tl = (i & 31) * 2;
        *(float2*)&out[((size_t)(n * CC + j) << 14)
                       + (size_t)((h0 + (tl >> 3)) * WW + w0 + (tl & 7))] =
            *(const float2*)&tr_s[j * 68 + tl];
    }
}

extern "C" void kernel_launch(void* const* d_in, const int* in_sizes, int n_in,
                              void* d_out, int out_size, void* d_ws, size_t ws_size,
                              hipStream_t stream) {
    const float* x      = (const float*)d_in[0];
    const float* qkv_w  = (const float*)d_in[1];
    const float* qkv_b  = (const float*)d_in[2];
    const float* proj_w = (const float*)d_in[3];
    const float* proj_b = (const float*)d_in[4];
    const float* rpb    = (const float*)d_in[5];
    const float* ln1_w  = (const float*)d_in[6];
    const float* ln1_b  = (const float*)d_in[7];
    const float* ln2_w  = (const float*)d_in[8];
    const float* ln2_b  = (const float*)d_in[9];
    const float* fc1_w  = (const float*)d_in[10];
    const float* fc1_b  = (const float*)d_in[11];
    const float* fc2_w  = (const float*)d_in[12];
    const float* fc2_b  = (const float*)d_in[13];
    float* out = (float*)d_out;
    char* ws = (char*)d_ws;

    _Float16* qkv16  = (_Float16*)(ws);                 // 12.58 MB [T][192]
    _Float16* pw16   = (_Float16*)(ws + 20971520);      //  8 KB
    _Float16* f1w16  = (_Float16*)(ws + 20979712);      // 32 KB
    _Float16* f2w16  = (_Float16*)(ws + 21012480);      // 32 KB

    k_qkvln   <<<256, 512, 0, stream>>>(x, ln1_w, ln1_b, qkv_w, qkv_b,
                                        proj_w, fc1_w, fc2_w,
                                        qkv16, pw16, f1w16, f2w16);
    k_attn_mlp<<<512, 512, 0, stream>>>(qkv16, rpb, pw16, proj_b, x, ln2_w, ln2_b,
                                        f1w16, fc1_b, f2w16, fc2_b, out);
}

// Round 6
// 122.998 us; speedup vs baseline: 1.4039x; 1.0074x over previous
//
#include <hip/hip_runtime.h>
#include <math.h>

#define TQ   32768
#define HWSZ 16384
#define CC   64
#define HH   128
#define WW   128
#define C3   192
#define C4   256
#define KS   7

typedef _Float16 half2v __attribute__((ext_vector_type(2)));
typedef _Float16 half4v __attribute__((ext_vector_type(4)));
typedef _Float16 half8v __attribute__((ext_vector_type(8)));
typedef float    f32x4  __attribute__((ext_vector_type(4)));

#define MFMA16(a, b, c) __builtin_amdgcn_mfma_f32_16x16x32_f16((a), (b), (c), 0, 0, 0)

// gelu tanh-form: max abs dev ~3e-4 vs erf, far under f16 rounding of H.
__device__ __forceinline__ float gelu_f(float v) {
    float z = v * (1.59576912f + 0.07135481f * v * v);
    float e = __expf(-z);
    return v * (1.f / (1.f + e));
}

// ============ K1: LN1 + QKV GEMM + weight-f16 preconvert. grid 256 x 512 thr ============
// Block->row mapping XCD-swizzled: row h runs on XCD (h>>3)%8, so K2 (whose tile th
// reads rows 8*th-3..8*th+10 from XCD th%8) finds the central 8 rows dirty in ITS L2.
__global__ __launch_bounds__(512) void k_qkvln(const float* __restrict__ x,
        const float* __restrict__ lnw, const float* __restrict__ lnb,
        const float* __restrict__ qw, const float* __restrict__ qb,
        const float* __restrict__ pw, const float* __restrict__ f1w,
        const float* __restrict__ f2w,
        _Float16* __restrict__ qkv16, _Float16* __restrict__ pw16,
        _Float16* __restrict__ f1w16, _Float16* __restrict__ f2w16) {
    __shared__ union {
        struct { __align__(16) _Float16 A[128 * 72]; __align__(16) _Float16 B[192 * 72]; } st;
        __align__(16) _Float16 outb[128 * 200];
    } u;
    __shared__ float ps1[512], ps2[512], m_s[128], r_s[128];
    __shared__ float w_s[64], b_s[64], bias_s[192];
    int tid = threadIdx.x;
    // XCD-locality swizzle: b -> (n_b, h) with XCD(b)=b&7 == (h>>3)&7
    int b = blockIdx.x;
    int xcd = b & 7, rest = b >> 3;
    int r8 = rest & 7, hi = rest >> 3;            // hi in [0,4)
    int g = xcd + 8 * (hi & 1);                   // row-group in [0,16)
    int n_b = hi >> 1;
    int t0 = (n_b << 14) + ((g * 8 + r8) << 7);   // 128 tokens = one image row
    if (tid < 64) { w_s[tid] = lnw[tid]; b_s[tid] = lnb[tid]; }
    if (tid < 192) bias_s[tid] = qb[tid];
    int tok = tid & 127, cq = tid >> 7;          // cq 0..3, 16 channels each
    int t = t0 + tok;
    int n = t >> 14, hw = t & (HWSZ - 1);
    const float* xr = x + ((size_t)n << 20) + hw;
    float v[16];
    float s = 0.f, s2 = 0.f;
#pragma unroll
    for (int e = 0; e < 16; ++e) {
        float f = xr[(cq * 16 + e) * HWSZ];
        v[e] = f; s += f; s2 += f * f;
    }
    ps1[tid] = s; ps2[tid] = s2;
    for (int i = tid; i < 3072; i += 512) {
        int jj = i >> 4, seg = i & 15;
        float4 v4 = *(const float4*)&qw[(size_t)jj * 64 + seg * 4];
        half4v h4 = { (_Float16)v4.x, (_Float16)v4.y, (_Float16)v4.z, (_Float16)v4.w };
        *(half4v*)&u.st.B[jj * 72 + seg * 4] = h4;
    }
    {
        int gg = blockIdx.x * 512 + tid;
        if (gg < 4096) pw16[gg] = (_Float16)pw[gg];
        else if (gg < 20480) f1w16[gg - 4096] = (_Float16)f1w[gg - 4096];
        else if (gg < 36864) f2w16[gg - 20480] = (_Float16)f2w[gg - 20480];
    }
    __syncthreads();
    if (tid < 128) {
        float ss = ps1[tid] + ps1[tid + 128] + ps1[tid + 256] + ps1[tid + 384];
        float qq = ps2[tid] + ps2[tid + 128] + ps2[tid + 256] + ps2[tid + 384];
        float m = ss * (1.f / 64.f);
        float var = qq * (1.f / 64.f) - m * m;
        m_s[tid] = m; r_s[tid] = rsqrtf(var + 1e-5f);
    }
    __syncthreads();
    {
        float m = m_s[tok], r = r_s[tok];
#pragma unroll
        for (int u8 = 0; u8 < 2; ++u8) {
            half8v o;
#pragma unroll
            for (int e = 0; e < 8; ++e) {
                int c = cq * 16 + u8 * 8 + e;
                o[e] = (_Float16)((v[u8 * 8 + e] - m) * r * w_s[c] + b_s[c]);
            }
            *(half8v*)&u.st.A[tok * 72 + cq * 16 + u8 * 8] = o;
        }
    }
    __syncthreads();
    int lane = tid & 63, wv = tid >> 6;          // 8 waves
    int quad = lane >> 4, l16 = lane & 15;
    int mt0 = (wv & 1) * 64, nt0 = (wv >> 1) * 48;
    f32x4 acc[4][3];
#pragma unroll
    for (int mf = 0; mf < 4; ++mf)
#pragma unroll
        for (int nf = 0; nf < 3; ++nf) acc[mf][nf] = (f32x4){0.f, 0.f, 0.f, 0.f};
#pragma unroll
    for (int ks = 0; ks < 64; ks += 32) {
        half8v a[4], bfr[3];
#pragma unroll
        for (int mf = 0; mf < 4; ++mf)
            a[mf] = *(const half8v*)&u.st.A[(mt0 + mf * 16 + l16) * 72 + ks + quad * 8];
#pragma unroll
        for (int nf = 0; nf < 3; ++nf)
            bfr[nf] = *(const half8v*)&u.st.B[(nt0 + nf * 16 + l16) * 72 + ks + quad * 8];
#pragma unroll
        for (int mf = 0; mf < 4; ++mf)
#pragma unroll
            for (int nf = 0; nf < 3; ++nf) acc[mf][nf] = MFMA16(a[mf], bfr[nf], acc[mf][nf]);
    }
    __syncthreads();
    const float qscale = 0.17677669529663687f;
#pragma unroll
    for (int mf = 0; mf < 4; ++mf)
#pragma unroll
        for (int nf = 0; nf < 3; ++nf) {
            int j = nt0 + nf * 16 + l16;
            float bias = bias_s[j];
            float sc = (j < 64) ? qscale : 1.f;
#pragma unroll
            for (int r = 0; r < 4; ++r) {
                int tl = mt0 + mf * 16 + quad * 4 + r;
                u.outb[tl * 200 + j] = (_Float16)((acc[mf][nf][r] + bias) * sc);
            }
        }
    __syncthreads();
    for (int i = tid; i < 4096; i += 512) {
        int tk = i >> 5, rem = i & 31;
        if (rem < 24)
            *(half8v*)&qkv16[(size_t)(t0 + tk) * C3 + rem * 8] =
                *(const half8v*)&u.outb[tk * 200 + rem * 8];
    }
}

// ============ K2: attention (barrier-free, reg+shfl) + proj + residual + LN2 + MLP ==========
// grid 512 x 512 thr; __launch_bounds__(512,4) -> 2 blocks/CU.
// XCD-locality: th = bx&15 -> XCD = th%8; all 64 blocks/XCD share one 14-row kv slab
// (1.8 MB, L2-resident) instead of streaming the full 8.4 MB kv array per XCD.
__global__ __launch_bounds__(512, 4) void k_attn_mlp(const _Float16* __restrict__ qkv16,
        const float* __restrict__ rpb,
        const _Float16* __restrict__ pw16, const float* __restrict__ pb,
        const float* __restrict__ x,
        const float* __restrict__ ln2w, const float* __restrict__ ln2b,
        const _Float16* __restrict__ f1w16, const float* __restrict__ f1b,
        const _Float16* __restrict__ f2w16, const float* __restrict__ f2b,
        float* __restrict__ out) {
    __shared__ __align__(16) char smem[78216];
    _Float16* kv_s  = (_Float16*)smem;
    _Float16* q_s   = (_Float16*)(smem + 53312);
    _Float16* s_s   = (_Float16*)(smem + 63552);  // pw stage (post-PV era only)
    float*    rpb_s = (float*)(smem + 76352);
    float* x2t  = (float*)smem;
    float* ps1  = (float*)(smem + 20480);
    float* ps2  = (float*)(smem + 22528);
    float* m_s  = (float*)(smem + 24576);
    float* r_s  = (float*)(smem + 24832);
    float* w_s  = (float*)(smem + 25088);
    float* b_s  = (float*)(smem + 25344);
    float* pb_s = (float*)(smem + 25600);
    _Float16* A2_s = (_Float16*)(smem + 53312);   // xn2 tile, aliases q_s
    _Float16* H_s  = (_Float16*)(smem + 17408);   // fc1 activations
    float*    tr_s = (float*)(smem + 17408);      // transpose staging, after H reads
    float*    f1b_s = (float*)(smem + 63552);
    float*    f2b_s = (float*)(smem + 64576);

    int tid = threadIdx.x;
    int bx = blockIdx.x;
    int n  = bx >> 8;
    int th = bx & 15, tw = (bx >> 4) & 15;        // swapped: XCD = th%8
    int h0 = th * 8, w0 = tw * 8;
    int wr0 = min(max(h0 - 3, 0), HH - 14);
    int ww0 = min(max(w0 - 3, 0), WW - 14);
    int tbase = n << 14;
    int lane = tid & 63, wvi = tid >> 6;          // 8 waves
    int quad = lane >> 4, l16 = lane & 15;

    for (int i = tid; i < 338; i += 512) rpb_s[i] = rpb[i];
    for (int i = tid; i < 196 * 16; i += 512) {
        int tk = i >> 4, u = i & 15;
        int wi = tk / 14, wj = tk - wi * 14;
        *(half8v*)&kv_s[tk * 136 + u * 8] = *(const half8v*)&qkv16[
            (size_t)(tbase + (wr0 + wi) * WW + ww0 + wj) * C3 + 64 + u * 8];
    }
    {
        int q8 = tid >> 3, u8 = tid & 7;
        int qg = tbase + (h0 + (q8 >> 3)) * WW + (w0 + (q8 & 7));
        *(half8v*)&q_s[q8 * 80 + u8 * 8] = *(const half8v*)&qkv16[(size_t)qg * C3 + u8 * 8];
    }
    // prefetch proj weights into registers (8KB over 512 thr) — staged to LDS after PV
    half8v pwr = *(const half8v*)&pw16[(size_t)tid * 8];
    __syncthreads();

    int p4 = tid & 3, z = (tid >> 2) & 1, q = tid >> 3;   // q 0..63; group of 4 lanes = 1 row
    int qy = q >> 3, qx = q & 7;
    int h = h0 + qy, wc = w0 + qx;
    int sh = min(max(h - 3, 0), HH - KS);
    int sw = min(max(wc - 3, 0), WW - KS);
    int oh = sh - wr0, ow = sw - ww0;
    int dhp = h - sh + 6, dwp = wc - sw + 6;

    // ---- QK^T + bias -> registers (13 scores/thread); no LDS, no barrier ----
    float ereg[13];
    float inv;
    {
        const half8v* qp = (const half8v*)&q_s[q * 80 + z * 32];
        half8v q0 = qp[0], q1 = qp[1], q2 = qp[2], q3 = qp[3];
        float mx = -1e30f;
        int i7 = 0, j7 = p4;
#pragma unroll
        for (int k = 0; k < 13; ++k) {
            int nb = p4 + 4 * k;
            if (nb < 49) {
                int tk = (oh + i7) * 14 + (ow + j7);
                const half8v* kp = (const half8v*)&kv_s[tk * 136 + z * 32];
                half2v acc2 = { (_Float16)0.f, (_Float16)0.f };
                half8v k0 = kp[0], k1 = kp[1], k2 = kp[2], k3 = kp[3];
                acc2 += (half2v){k0.s0, k0.s1} * (half2v){q0.s0, q0.s1};
                acc2 += (half2v){k0.s2, k0.s3} * (half2v){q0.s2, q0.s3};
                acc2 += (half2v){k0.s4, k0.s5} * (half2v){q0.s4, q0.s5};
                acc2 += (half2v){k0.s6, k0.s7} * (half2v){q0.s6, q0.s7};
                acc2 += (half2v){k1.s0, k1.s1} * (half2v){q1.s0, q1.s1};
                acc2 += (half2v){k1.s2, k1.s3} * (half2v){q1.s2, q1.s3};
                acc2 += (half2v){k1.s4, k1.s5} * (half2v){q1.s4, q1.s5};
                acc2 += (half2v){k1.s6, k1.s7} * (half2v){q1.s6, q1.s7};
                acc2 += (half2v){k2.s0, k2.s1} * (half2v){q2.s0, q2.s1};
                acc2 += (half2v){k2.s2, k2.s3} * (half2v){q2.s2, q2.s3};
                acc2 += (half2v){k2.s4, k2.s5} * (half2v){q2.s4, q2.s5};
                acc2 += (half2v){k2.s6, k2.s7} * (half2v){q2.s6, q2.s7};
                acc2 += (half2v){k3.s0, k3.s1} * (half2v){q3.s0, q3.s1};
                acc2 += (half2v){k3.s2, k3.s3} * (half2v){q3.s2, q3.s3};
                acc2 += (half2v){k3.s4, k3.s5} * (half2v){q3.s4, q3.s5};
                acc2 += (half2v){k3.s6, k3.s7} * (half2v){q3.s6, q3.s7};
                ereg[k] = (float)acc2.x + (float)acc2.y
                        + rpb_s[(z * 13 + (dhp - i7)) * 13 + (dwp - j7)];
                mx = fmaxf(mx, ereg[k]);
                j7 += 4;
                if (j7 >= 7) { j7 -= 7; ++i7; }
            } else {
                ereg[k] = -1e30f;
            }
        }
        // row max across the 4-lane group
        mx = fmaxf(mx, __shfl_xor(mx, 1));
        mx = fmaxf(mx, __shfl_xor(mx, 2));
        float sum = 0.f;
#pragma unroll
        for (int k = 0; k < 13; ++k) {
            int nb = p4 + 4 * k;
            if (nb < 49) {
                float e = __expf(ereg[k] - mx);
                ereg[k] = e;
                sum += e;
            }
        }
        sum += __shfl_xor(sum, 1);
        sum += __shfl_xor(sum, 2);
        inv = 1.f / sum;
    }

    // ---- PV: p broadcast via width-4 shfl; 8 channels/thread; no barrier ----
    {
        int c8 = p4;
        half2v acc[4];
#pragma unroll
        for (int j = 0; j < 4; ++j) acc[j] = (half2v){ (_Float16)0.f, (_Float16)0.f };
#pragma unroll
        for (int nb = 0; nb < 49; ++nb) {
            float pf = __shfl(ereg[nb >> 2], nb & 3, 4);
            int tk = (oh + nb / 7) * 14 + (ow + nb % 7);
            _Float16 p = (_Float16)pf;
            half2v p2 = { p, p };
            half8v v0 = *(const half8v*)&kv_s[tk * 136 + 64 + z * 32 + c8 * 8];
            acc[0] += (half2v){v0.s0, v0.s1} * p2;
            acc[1] += (half2v){v0.s2, v0.s3} * p2;
            acc[2] += (half2v){v0.s4, v0.s5} * p2;
            acc[3] += (half2v){v0.s6, v0.s7} * p2;
        }
        half8v o0;
#pragma unroll
        for (int j = 0; j < 4; ++j) {
            o0[2 * j]     = (_Float16)((float)acc[j].x * inv);
            o0[2 * j + 1] = (_Float16)((float)acc[j].y * inv);
        }
        *(half8v*)(q_s + q * 72 + z * 32 + c8 * 8) = o0;
    }
    __syncthreads();
    // proj weights: LDS write from prefetched regs
    *(half8v*)&s_s[(tid >> 3) * 72 + (tid & 7) * 8] = pwr;
    if (tid < 64) { w_s[tid] = ln2w[tid]; b_s[tid] = ln2b[tid]; pb_s[tid] = pb[tid]; }
    __syncthreads();
    // ---- proj + residual -> x2t: 8 waves x (16 tok x 32 j) ----
    {
        int mt0 = (wvi & 3) * 16, n0 = (wvi >> 2) * 32;
        f32x4 acc2[2];
#pragma unroll
        for (int nf = 0; nf < 2; ++nf) acc2[nf] = (f32x4){0.f, 0.f, 0.f, 0.f};
#pragma unroll
        for (int ks = 0; ks < 64; ks += 32) {
            half8v a = *(const half8v*)&q_s[(mt0 + l16) * 72 + ks + quad * 8];
            half8v bfr[2];
#pragma unroll
            for (int nf = 0; nf < 2; ++nf)
                bfr[nf] = *(const half8v*)&s_s[(n0 + nf * 16 + l16) * 72 + ks + quad * 8];
#pragma unroll
            for (int nf = 0; nf < 2; ++nf) acc2[nf] = MFMA16(a, bfr[nf], acc2[nf]);
        }
        __syncthreads();
        int tl0 = mt0 + quad * 4;
        int hwl = (h0 + (tl0 >> 3)) * WW + w0 + (tl0 & 7);
#pragma unroll
        for (int nf = 0; nf < 2; ++nf) {
            int j = n0 + nf * 16 + l16;
            float bias = pb_s[j];
            float4 rx = *(const float4*)&x[((size_t)(n * CC + j) << 14) + hwl];
#pragma unroll
            for (int r = 0; r < 4; ++r)
                x2t[(tl0 + r) * 68 + j] = acc2[nf][r] + bias + ((const float*)&rx)[r];
        }
    }
    if (tid < 256) f1b_s[tid] = f1b[tid];
    else if (tid < 320) f2b_s[tid - 256] = f2b[tid - 256];
    __syncthreads();
    int tok = tid & 63, cq = tid >> 6;            // cq 0..7, 8 channels each
    {
        float s = 0.f, s2 = 0.f;
#pragma unroll
        for (int e = 0; e < 8; ++e) {
            float f = x2t[tok * 68 + cq * 8 + e];
            s += f; s2 += f * f;
        }
        ps1[tid] = s; ps2[tid] = s2;
    }
    __syncthreads();
    if (tid < 64) {
        float ss = 0.f, qq = 0.f;
#pragma unroll
        for (int k = 0; k < 8; ++k) { ss += ps1[tid + 64 * k]; qq += ps2[tid + 64 * k]; }
        float m = ss * (1.f / 64.f);
        float var = qq * (1.f / 64.f) - m * m;
        m_s[tid] = m; r_s[tid] = rsqrtf(var + 1e-5f);
    }
    __syncthreads();
    // LN2 -> A2_s (stays in LDS)
    {
        float m = m_s[tok], r = r_s[tok];
        half8v nv0;
#pragma unroll
        for (int e = 0; e < 8; ++e) {
            int c = cq * 8 + e;
            float f = x2t[tok * 68 + c];
            nv0[e] = (_Float16)((f - m) * r * w_s[c] + b_s[c]);
        }
        *(half8v*)&A2_s[tok * 72 + cq * 8] = nv0;
    }
    __syncthreads();   // A2 ready; x2t/w/b consumed before H clobbers
    // ---- fc1: 8 waves x (32 tok x 64 j); W1 f16 from L2 ----
    {
        int mt0 = (wvi & 1) * 32, nt1 = (wvi >> 1) * 64;
        f32x4 acc[2][4];
#pragma unroll
        for (int mf = 0; mf < 2; ++mf)
#pragma unroll
            for (int nf = 0; nf < 4; ++nf) acc[mf][nf] = (f32x4){0.f, 0.f, 0.f, 0.f};
#pragma unroll
        for (int ks = 0; ks < 64; ks += 32) {
            half8v a[2], bfr[4];
#pragma unroll
            for (int mf = 0; mf < 2; ++mf)
                a[mf] = *(const half8v*)&A2_s[(mt0 + mf * 16 + l16) * 72 + ks + quad * 8];
#pragma unroll
            for (int nf = 0; nf < 4; ++nf)
                bfr[nf] = *(const half8v*)&f1w16[(size_t)(nt1 + nf * 16 + l16) * 64 + ks + quad * 8];
#pragma unroll
            for (int mf = 0; mf < 2; ++mf)
#pragma unroll
                for (int nf = 0; nf < 4; ++nf) acc[mf][nf] = MFMA16(a[mf], bfr[nf], acc[mf][nf]);
        }
#pragma unroll
        for (int mf = 0; mf < 2; ++mf)
#pragma unroll
            for (int nf = 0; nf < 4; ++nf) {
                int jl = nt1 + nf * 16 + l16;
                float bias = f1b_s[jl];
#pragma unroll
                for (int r = 0; r < 4; ++r) {
                    int tl = mt0 + mf * 16 + quad * 4 + r;
                    H_s[tl * 264 + jl] = (_Float16)gelu_f(acc[mf][nf][r] + bias);
                }
            }
    }
    __syncthreads();   // H complete
    // ---- fc2: 8 waves x (16 tok x 32 j), K=256; W2 f16 from L2 ----
    {
        int mt = (wvi & 3) * 16, n0 = (wvi >> 2) * 32;
        f32x4 acc2[2];
#pragma unroll
        for (int nf = 0; nf < 2; ++nf) acc2[nf] = (f32x4){0.f, 0.f, 0.f, 0.f};
#pragma unroll
        for (int ks = 0; ks < 256; ks += 32) {
            half8v a = *(const half8v*)&H_s[(mt + l16) * 264 + ks + quad * 8];
            half8v bfr[2];
#pragma unroll
            for (int nf = 0; nf < 2; ++nf)
                bfr[nf] = *(const half8v*)&f2w16[(size_t)(n0 + nf * 16 + l16) * 256 + ks + quad * 8];
#pragma unroll
            for (int nf = 0; nf < 2; ++nf) acc2[nf] = MFMA16(a, bfr[nf], acc2[nf]);
        }
        __syncthreads();   // all H reads done -> tr overwrite safe
#pragma unroll
        for (int nf = 0; nf < 2; ++nf) {
            int j = n0 + nf * 16 + l16;
            float bias = f2b_s[j];
#pragma unroll
            for (int r = 0; r < 4; ++r) {
                int tl = mt + quad * 4 + r;
                float v = acc2[nf][r] + bias + x2t[tl * 68 + j];
                tr_s[j * 68 + tl] = v;
            }
        }
    }
    __syncthreads();   // tr complete
    // ---- NCHW stores ----
    for (int i = tid; i < 2048; i += 512) {
        int j = i >> 5, tl = (i & 31) * 2;
        *(float2*)&out[((size_t)(n * CC + j) << 14)
                       + (size_t)((h0 + (tl >> 3)) * WW + w0 + (tl & 7))] =
            *(const float2*)&tr_s[j * 68 + tl];
    }
}

extern "C" void kernel_launch(void* const* d_in, const int* in_sizes, int n_in,
                              void* d_out, int out_size, void* d_ws, size_t ws_size,
                              hipStream_t stream) {
    const float* x      = (const float*)d_in[0];
    const float* qkv_w  = (const float*)d_in[1];
    const float* qkv_b  = (const float*)d_in[2];
    const float* proj_w = (const float*)d_in[3];
    const float* proj_b = (const float*)d_in[4];
    const float* rpb    = (const float*)d_in[5];
    const float* ln1_w  = (const float*)d_in[6];
    const float* ln1_b  = (const float*)d_in[7];
    const float* ln2_w  = (const float*)d_in[8];
    const float* ln2_b  = (const float*)d_in[9];
    const float* fc1_w  = (const float*)d_in[10];
    const float* fc1_b  = (const float*)d_in[11];
    const float* fc2_w  = (const float*)d_in[12];
    const float* fc2_b  = (const float*)d_in[13];
    float* out = (float*)d_out;
    char* ws = (char*)d_ws;

    _Float16* qkv16  = (_Float16*)(ws);                 // 12.58 MB [T][192]
    _Float16* pw16   = (_Float16*)(ws + 20971520);      //  8 KB
    _Float16* f1w16  = (_Float16*)(ws + 20979712);      // 32 KB
    _Float16* f2w16  = (_Float16*)(ws + 21012480);      // 32 KB

    k_qkvln   <<<256, 512, 0, stream>>>(x, ln1_w, ln1_b, qkv_w, qkv_b,
                                        proj_w, fc1_w, fc2_w,
                                        qkv16, pw16, f1w16, f2w16);
    k_attn_mlp<<<512, 512, 0, stream>>>(qkv16, rpb, pw16, proj_b, x, ln2_w, ln2_b,
                                        f1w16, fc1_b, f2w16, fc2_b, out);
}

// Round 8
// 121.510 us; speedup vs baseline: 1.4211x; 1.0122x over previous
//
#include <hip/hip_runtime.h>
#include <math.h>

#define TQ   32768
#define HWSZ 16384
#define CC   64
#define HH   128
#define WW   128
#define C3   192
#define C4   256
#define KS   7

typedef _Float16 half2v __attribute__((ext_vector_type(2)));
typedef _Float16 half4v __attribute__((ext_vector_type(4)));
typedef _Float16 half8v __attribute__((ext_vector_type(8)));
typedef float    f32x4  __attribute__((ext_vector_type(4)));

#define MFMA16(a, b, c) __builtin_amdgcn_mfma_f32_16x16x32_f16((a), (b), (c), 0, 0, 0)

// gelu tanh-form: max abs dev ~3e-4 vs erf, far under f16 rounding of H.
__device__ __forceinline__ float gelu_f(float v) {
    float z = v * (1.59576912f + 0.07135481f * v * v);
    float e = __expf(-z);
    return v * (1.f / (1.f + e));
}

// ============ K1: LN1 + QKV GEMM + weight-f16 preconvert. grid 256 x 512 thr ============
// Block->row mapping XCD-swizzled: row h runs on XCD (h>>3)%8 so K2 tile th (XCD th%8)
// finds its central rows dirty in its own L2.
__global__ __launch_bounds__(512) void k_qkvln(const float* __restrict__ x,
        const float* __restrict__ lnw, const float* __restrict__ lnb,
        const float* __restrict__ qw, const float* __restrict__ qb,
        const float* __restrict__ pw, const float* __restrict__ f1w,
        const float* __restrict__ f2w,
        _Float16* __restrict__ qkv16, _Float16* __restrict__ pw16,
        _Float16* __restrict__ f1w16, _Float16* __restrict__ f2w16) {
    __shared__ union {
        struct { __align__(16) _Float16 A[128 * 72]; __align__(16) _Float16 B[192 * 72]; } st;
        __align__(16) _Float16 outb[128 * 200];
    } u;
    __shared__ float ps1[512], ps2[512], m_s[128], r_s[128];
    __shared__ float w_s[64], b_s[64], bias_s[192];
    int tid = threadIdx.x;
    // XCD-locality swizzle: b -> (n_b, h) with XCD(b)=b&7 == (h>>3)&7
    int b = blockIdx.x;
    int xcd = b & 7, rest = b >> 3;
    int r8 = rest & 7, hi = rest >> 3;            // hi in [0,4)
    int g = xcd + 8 * (hi & 1);                   // row-group in [0,16)
    int n_b = hi >> 1;
    int t0 = (n_b << 14) + ((g * 8 + r8) << 7);   // 128 tokens = one image row
    if (tid < 64) { w_s[tid] = lnw[tid]; b_s[tid] = lnb[tid]; }
    if (tid < 192) bias_s[tid] = qb[tid];
    int tok = tid & 127, cq = tid >> 7;          // cq 0..3, 16 channels each
    int t = t0 + tok;
    int n = t >> 14, hw = t & (HWSZ - 1);
    const float* xr = x + ((size_t)n << 20) + hw;
    float v[16];
    float s = 0.f, s2 = 0.f;
#pragma unroll
    for (int e = 0; e < 16; ++e) {
        float f = xr[(cq * 16 + e) * HWSZ];
        v[e] = f; s += f; s2 += f * f;
    }
    ps1[tid] = s; ps2[tid] = s2;
    for (int i = tid; i < 3072; i += 512) {
        int jj = i >> 4, seg = i & 15;
        float4 v4 = *(const float4*)&qw[(size_t)jj * 64 + seg * 4];
        half4v h4 = { (_Float16)v4.x, (_Float16)v4.y, (_Float16)v4.z, (_Float16)v4.w };
        *(half4v*)&u.st.B[jj * 72 + seg * 4] = h4;
    }
    {
        int gg = blockIdx.x * 512 + tid;
        if (gg < 4096) pw16[gg] = (_Float16)pw[gg];
        else if (gg < 20480) f1w16[gg - 4096] = (_Float16)f1w[gg - 4096];
        else if (gg < 36864) f2w16[gg - 20480] = (_Float16)f2w[gg - 20480];
    }
    __syncthreads();
    if (tid < 128) {
        float ss = ps1[tid] + ps1[tid + 128] + ps1[tid + 256] + ps1[tid + 384];
        float qq = ps2[tid] + ps2[tid + 128] + ps2[tid + 256] + ps2[tid + 384];
        float m = ss * (1.f / 64.f);
        float var = qq * (1.f / 64.f) - m * m;
        m_s[tid] = m; r_s[tid] = rsqrtf(var + 1e-5f);
    }
    __syncthreads();
    {
        float m = m_s[tok], r = r_s[tok];
#pragma unroll
        for (int u8 = 0; u8 < 2; ++u8) {
            half8v o;
#pragma unroll
            for (int e = 0; e < 8; ++e) {
                int c = cq * 16 + u8 * 8 + e;
                o[e] = (_Float16)((v[u8 * 8 + e] - m) * r * w_s[c] + b_s[c]);
            }
            *(half8v*)&u.st.A[tok * 72 + cq * 16 + u8 * 8] = o;
        }
    }
    __syncthreads();
    int lane = tid & 63, wv = tid >> 6;          // 8 waves
    int quad = lane >> 4, l16 = lane & 15;
    int mt0 = (wv & 1) * 64, nt0 = (wv >> 1) * 48;
    f32x4 acc[4][3];
#pragma unroll
    for (int mf = 0; mf < 4; ++mf)
#pragma unroll
        for (int nf = 0; nf < 3; ++nf) acc[mf][nf] = (f32x4){0.f, 0.f, 0.f, 0.f};
#pragma unroll
    for (int ks = 0; ks < 64; ks += 32) {
        half8v a[4], bfr[3];
#pragma unroll
        for (int mf = 0; mf < 4; ++mf)
            a[mf] = *(const half8v*)&u.st.A[(mt0 + mf * 16 + l16) * 72 + ks + quad * 8];
#pragma unroll
        for (int nf = 0; nf < 3; ++nf)
            bfr[nf] = *(const half8v*)&u.st.B[(nt0 + nf * 16 + l16) * 72 + ks + quad * 8];
#pragma unroll
        for (int mf = 0; mf < 4; ++mf)
#pragma unroll
            for (int nf = 0; nf < 3; ++nf) acc[mf][nf] = MFMA16(a[mf], bfr[nf], acc[mf][nf]);
    }
    __syncthreads();
    const float qscale = 0.17677669529663687f;
#pragma unroll
    for (int mf = 0; mf < 4; ++mf)
#pragma unroll
        for (int nf = 0; nf < 3; ++nf) {
            int j = nt0 + nf * 16 + l16;
            float bias = bias_s[j];
            float sc = (j < 64) ? qscale : 1.f;
#pragma unroll
            for (int r = 0; r < 4; ++r) {
                int tl = mt0 + mf * 16 + quad * 4 + r;
                u.outb[tl * 200 + j] = (_Float16)((acc[mf][nf][r] + bias) * sc);
            }
        }
    __syncthreads();
    for (int i = tid; i < 4096; i += 512) {
        int tk = i >> 5, rem = i & 31;
        if (rem < 24)
            *(half8v*)&qkv16[(size_t)(t0 + tk) * C3 + rem * 8] =
                *(const half8v*)&u.outb[tk * 200 + rem * 8];
    }
}

// ============ K2: attention (K-only LDS, V direct from L2) + proj + LN2 + MLP ==========
// grid 512 x 512 thr; __launch_bounds__(512,4) -> 2 blocks/CU; XCD = th%8 (kv slab L2-res).
// V is NOT staged: after the XCD swizzle the per-XCD kv slab (~1.8MB) is L2-resident, so
// PV reads V straight from qkv16 (m169 precedent: don't stage what L2 already holds).
// LDS plan (smem[78216]):
//   attention era: k_s@0(28224) q_s@53312(10240) rpb@76352
//   post-attn era: x2t@0(17408) ps1@20480 ps2@22528 m@24576 r@24832 w@25088 b@25344
//                  pb@25600 | pw-stage s_s@63552 | A2@53312 f1b@63552 f2b@64576
//   MLP era:       H@17408(33792)  tr@17408(after H reads)
__global__ __launch_bounds__(512, 4) void k_attn_mlp(const _Float16* __restrict__ qkv16,
        const float* __restrict__ rpb,
        const _Float16* __restrict__ pw16, const float* __restrict__ pb,
        const float* __restrict__ x,
        const float* __restrict__ ln2w, const float* __restrict__ ln2b,
        const _Float16* __restrict__ f1w16, const float* __restrict__ f1b,
        const _Float16* __restrict__ f2w16, const float* __restrict__ f2b,
        float* __restrict__ out) {
    __shared__ __align__(16) char smem[78216];
    _Float16* k_s   = (_Float16*)smem;            // [196][72] K channels only
    _Float16* q_s   = (_Float16*)(smem + 53312);
    _Float16* s_s   = (_Float16*)(smem + 63552);  // pw stage (post-PV era only)
    float*    rpb_s = (float*)(smem + 76352);
    float* x2t  = (float*)smem;
    float* ps1  = (float*)(smem + 20480);
    float* ps2  = (float*)(smem + 22528);
    float* m_s  = (float*)(smem + 24576);
    float* r_s  = (float*)(smem + 24832);
    float* w_s  = (float*)(smem + 25088);
    float* b_s  = (float*)(smem + 25344);
    float* pb_s = (float*)(smem + 25600);
    _Float16* A2_s = (_Float16*)(smem + 53312);   // xn2 tile, aliases q_s
    _Float16* H_s  = (_Float16*)(smem + 17408);   // fc1 activations
    float*    tr_s = (float*)(smem + 17408);      // transpose staging, after H reads
    float*    f1b_s = (float*)(smem + 63552);
    float*    f2b_s = (float*)(smem + 64576);

    int tid = threadIdx.x;
    int bx = blockIdx.x;
    int n  = bx >> 8;
    int th = bx & 15, tw = (bx >> 4) & 15;        // XCD = th%8
    int h0 = th * 8, w0 = tw * 8;
    int wr0 = min(max(h0 - 3, 0), HH - 14);
    int ww0 = min(max(w0 - 3, 0), WW - 14);
    int tbase = n << 14;
    int lane = tid & 63, wvi = tid >> 6;          // 8 waves
    int quad = lane >> 4, l16 = lane & 15;

    for (int i = tid; i < 338; i += 512) rpb_s[i] = rpb[i];
    // stage K only: 196 tokens x 64 ch (25KB) — half the old staging
    for (int i = tid; i < 196 * 8; i += 512) {
        int tk = i >> 3, u = i & 7;
        int wi = tk / 14, wj = tk - wi * 14;
        *(half8v*)&k_s[tk * 72 + u * 8] = *(const half8v*)&qkv16[
            (size_t)(tbase + (wr0 + wi) * WW + ww0 + wj) * C3 + 64 + u * 8];
    }
    {
        int q8 = tid >> 3, u8 = tid & 7;
        int qg = tbase + (h0 + (q8 >> 3)) * WW + (w0 + (q8 & 7));
        *(half8v*)&q_s[q8 * 80 + u8 * 8] = *(const half8v*)&qkv16[(size_t)qg * C3 + u8 * 8];
    }
    // prefetch proj weights into registers (8KB over 512 thr) — staged to LDS after PV
    half8v pwr = *(const half8v*)&pw16[(size_t)tid * 8];
    __syncthreads();

    int p4 = tid & 3, z = (tid >> 2) & 1, q = tid >> 3;   // 4 lanes handle one (q,z) row
    int qy = q >> 3, qx = q & 7;
    int h = h0 + qy, wc = w0 + qx;
    int sh = min(max(h - 3, 0), HH - KS);
    int sw = min(max(wc - 3, 0), WW - KS);
    int oh = sh - wr0, ow = sw - ww0;
    int dhp = h - sh + 6, dwp = wc - sw + 6;

    // ---- QK^T + bias -> registers (13 scores/thread); no LDS scores, no barrier ----
    float ereg[13];
    float inv;
    {
        const half8v* qp = (const half8v*)&q_s[q * 80 + z * 32];
        half8v q0 = qp[0], q1 = qp[1], q2 = qp[2], q3 = qp[3];
        float mx = -1e30f;
        int i7 = 0, j7 = p4;
#pragma unroll
        for (int k = 0; k < 13; ++k) {
            int nb = p4 + 4 * k;
            if (nb < 49) {
                int tk = (oh + i7) * 14 + (ow + j7);
                const half8v* kp = (const half8v*)&k_s[tk * 72 + z * 32];
                half2v acc2 = { (_Float16)0.f, (_Float16)0.f };
                half8v k0 = kp[0], k1 = kp[1], k2 = kp[2], k3 = kp[3];
                acc2 += (half2v){k0.s0, k0.s1} * (half2v){q0.s0, q0.s1};
                acc2 += (half2v){k0.s2, k0.s3} * (half2v){q0.s2, q0.s3};
                acc2 += (half2v){k0.s4, k0.s5} * (half2v){q0.s4, q0.s5};
                acc2 += (half2v){k0.s6, k0.s7} * (half2v){q0.s6, q0.s7};
                acc2 += (half2v){k1.s0, k1.s1} * (half2v){q1.s0, q1.s1};
                acc2 += (half2v){k1.s2, k1.s3} * (half2v){q1.s2, q1.s3};
                acc2 += (half2v){k1.s4, k1.s5} * (half2v){q1.s4, q1.s5};
                acc2 += (half2v){k1.s6, k1.s7} * (half2v){q1.s6, q1.s7};
                acc2 += (half2v){k2.s0, k2.s1} * (half2v){q2.s0, q2.s1};
                acc2 += (half2v){k2.s2, k2.s3} * (half2v){q2.s2, q2.s3};
                acc2 += (half2v){k2.s4, k2.s5} * (half2v){q2.s4, q2.s5};
                acc2 += (half2v){k2.s6, k2.s7} * (half2v){q2.s6, q2.s7};
                acc2 += (half2v){k3.s0, k3.s1} * (half2v){q3.s0, q3.s1};
                acc2 += (half2v){k3.s2, k3.s3} * (half2v){q3.s2, q3.s3};
                acc2 += (half2v){k3.s4, k3.s5} * (half2v){q3.s4, q3.s5};
                acc2 += (half2v){k3.s6, k3.s7} * (half2v){q3.s6, q3.s7};
                ereg[k] = (float)acc2.x + (float)acc2.y
                        + rpb_s[(z * 13 + (dhp - i7)) * 13 + (dwp - j7)];
                mx = fmaxf(mx, ereg[k]);
                j7 += 4;
                if (j7 >= 7) { j7 -= 7; ++i7; }
            } else {
                ereg[k] = -1e30f;
            }
        }
        mx = fmaxf(mx, __shfl_xor(mx, 1));
        mx = fmaxf(mx, __shfl_xor(mx, 2));
        float sum = 0.f;
#pragma unroll
        for (int k = 0; k < 13; ++k) {
            int nb = p4 + 4 * k;
            if (nb < 49) {
                float e = __expf(ereg[k] - mx);
                ereg[k] = e;
                sum += e;
            }
        }
        sum += __shfl_xor(sum, 1);
        sum += __shfl_xor(sum, 2);
        inv = 1.f / sum;
    }

    // ---- PV: V straight from qkv16 (L2-resident slab); p via width-4 shfl ----
    {
        int c8 = p4;
        const _Float16* vbase = qkv16
            + (size_t)(tbase + sh * WW + sw) * C3 + 128 + z * 32 + c8 * 8;
        half2v acc[4];
#pragma unroll
        for (int j = 0; j < 4; ++j) acc[j] = (half2v){ (_Float16)0.f, (_Float16)0.f };
#pragma unroll
        for (int nb = 0; nb < 49; ++nb) {
            float pf = __shfl(ereg[nb >> 2], nb & 3, 4);
            _Float16 p = (_Float16)pf;
            half2v p2 = { p, p };
            half8v v0 = *(const half8v*)&vbase[((nb / 7) * WW + (nb % 7)) * C3];
            acc[0] += (half2v){v0.s0, v0.s1} * p2;
            acc[1] += (half2v){v0.s2, v0.s3} * p2;
            acc[2] += (half2v){v0.s4, v0.s5} * p2;
            acc[3] += (half2v){v0.s6, v0.s7} * p2;
        }
        half8v o0;
#pragma unroll
        for (int j = 0; j < 4; ++j) {
            o0[2 * j]     = (_Float16)((float)acc[j].x * inv);
            o0[2 * j + 1] = (_Float16)((float)acc[j].y * inv);
        }
        *(half8v*)(q_s + q * 72 + z * 32 + c8 * 8) = o0;
    }
    __syncthreads();
    // proj weights: LDS write from prefetched regs
    *(half8v*)&s_s[(tid >> 3) * 72 + (tid & 7) * 8] = pwr;
    if (tid < 64) { w_s[tid] = ln2w[tid]; b_s[tid] = ln2b[tid]; pb_s[tid] = pb[tid]; }
    __syncthreads();
    // ---- proj + residual -> x2t: 8 waves x (16 tok x 32 j) ----
    {
        int mt0 = (wvi & 3) * 16, n0 = (wvi >> 2) * 32;
        f32x4 acc2[2];
#pragma unroll
        for (int nf = 0; nf < 2; ++nf) acc2[nf] = (f32x4){0.f, 0.f, 0.f, 0.f};
#pragma unroll
        for (int ks = 0; ks < 64; ks += 32) {
            half8v a = *(const half8v*)&q_s[(mt0 + l16) * 72 + ks + quad * 8];
            half8v bfr[2];
#pragma unroll
            for (int nf = 0; nf < 2; ++nf)
                bfr[nf] = *(const half8v*)&s_s[(n0 + nf * 16 + l16) * 72 + ks + quad * 8];
#pragma unroll
            for (int nf = 0; nf < 2; ++nf) acc2[nf] = MFMA16(a, bfr[nf], acc2[nf]);
        }
        __syncthreads();
        int tl0 = mt0 + quad * 4;
        int hwl = (h0 + (tl0 >> 3)) * WW + w0 + (tl0 & 7);
#pragma unroll
        for (int nf = 0; nf < 2; ++nf) {
            int j = n0 + nf * 16 + l16;
            float bias = pb_s[j];
            float4 rx = *(const float4*)&x[((size_t)(n * CC + j) << 14) + hwl];
#pragma unroll
            for (int r = 0; r < 4; ++r)
                x2t[(tl0 + r) * 68 + j] = acc2[nf][r] + bias + ((const float*)&rx)[r];
        }
    }
    if (tid < 256) f1b_s[tid] = f1b[tid];
    else if (tid < 320) f2b_s[tid - 256] = f2b[tid - 256];
    __syncthreads();
    int tok = tid & 63, cq = tid >> 6;            // cq 0..7, 8 channels each
    {
        float s = 0.f, s2 = 0.f;
#pragma unroll
        for (int e = 0; e < 8; ++e) {
            float f = x2t[tok * 68 + cq * 8 + e];
            s += f; s2 += f * f;
        }
        ps1[tid] = s; ps2[tid] = s2;
    }
    __syncthreads();
    if (tid < 64) {
        float ss = 0.f, qq = 0.f;
#pragma unroll
        for (int k = 0; k < 8; ++k) { ss += ps1[tid + 64 * k]; qq += ps2[tid + 64 * k]; }
        float m = ss * (1.f / 64.f);
        float var = qq * (1.f / 64.f) - m * m;
        m_s[tid] = m; r_s[tid] = rsqrtf(var + 1e-5f);
    }
    __syncthreads();
    // LN2 -> A2_s (stays in LDS)
    {
        float m = m_s[tok], r = r_s[tok];
        half8v nv0;
#pragma unroll
        for (int e = 0; e < 8; ++e) {
            int c = cq * 8 + e;
            float f = x2t[tok * 68 + c];
            nv0[e] = (_Float16)((f - m) * r * w_s[c] + b_s[c]);
        }
        *(half8v*)&A2_s[tok * 72 + cq * 8] = nv0;
    }
    __syncthreads();   // A2 ready; x2t/w/b consumed before H clobbers
    // ---- fc1: 8 waves x (32 tok x 64 j); W1 f16 from L2 ----
    {
        int mt0 = (wvi & 1) * 32, nt1 = (wvi >> 1) * 64;
        f32x4 acc[2][4];
#pragma unroll
        for (int mf = 0; mf < 2; ++mf)
#pragma unroll
            for (int nf = 0; nf < 4; ++nf) acc[mf][nf] = (f32x4){0.f, 0.f, 0.f, 0.f};
#pragma unroll
        for (int ks = 0; ks < 64; ks += 32) {
            half8v a[2], bfr[4];
#pragma unroll
            for (int mf = 0; mf < 2; ++mf)
                a[mf] = *(const half8v*)&A2_s[(mt0 + mf * 16 + l16) * 72 + ks + quad * 8];
#pragma unroll
            for (int nf = 0; nf < 4; ++nf)
                bfr[nf] = *(const half8v*)&f1w16[(size_t)(nt1 + nf * 16 + l16) * 64 + ks + quad * 8];
#pragma unroll
            for (int mf = 0; mf < 2; ++mf)
#pragma unroll
                for (int nf = 0; nf < 4; ++nf) acc[mf][nf] = MFMA16(a[mf], bfr[nf], acc[mf][nf]);
        }
#pragma unroll
        for (int mf = 0; mf < 2; ++mf)
#pragma unroll
            for (int nf = 0; nf < 4; ++nf) {
                int jl = nt1 + nf * 16 + l16;
                float bias = f1b_s[jl];
#pragma unroll
                for (int r = 0; r < 4; ++r) {
                    int tl = mt0 + mf * 16 + quad * 4 + r;
                    H_s[tl * 264 + jl] = (_Float16)gelu_f(acc[mf][nf][r] + bias);
                }
            }
    }
    __syncthreads();   // H complete
    // ---- fc2: 8 waves x (16 tok x 32 j), K=256; W2 f16 from L2 ----
    {
        int mt = (wvi & 3) * 16, n0 = (wvi >> 2) * 32;
        f32x4 acc2[2];
#pragma unroll
        for (int nf = 0; nf < 2; ++nf) acc2[nf] = (f32x4){0.f, 0.f, 0.f, 0.f};
#pragma unroll
        for (int ks = 0; ks < 256; ks += 32) {
            half8v a = *(const half8v*)&H_s[(mt + l16) * 264 + ks + quad * 8];
            half8v bfr[2];
#pragma unroll
            for (int nf = 0; nf < 2; ++nf)
                bfr[nf] = *(const half8v*)&f2w16[(size_t)(n0 + nf * 16 + l16) * 256 + ks + quad * 8];
#pragma unroll
            for (int nf = 0; nf < 2; ++nf) acc2[nf] = MFMA16(a, bfr[nf], acc2[nf]);
        }
        __syncthreads();   // all H reads done -> tr overwrite safe
#pragma unroll
        for (int nf = 0; nf < 2; ++nf) {
            int j = n0 + nf * 16 + l16;
            float bias = f2b_s[j];
#pragma unroll
            for (int r = 0; r < 4; ++r) {
                int tl = mt + quad * 4 + r;
                float v = acc2[nf][r] + bias + x2t[tl * 68 + j];
                tr_s[j * 68 + tl] = v;
            }
        }
    }
    __syncthreads();   // tr complete
    // ---- NCHW stores ----
    for (int i = tid; i < 2048; i += 512) {
        int j = i >> 5, tl = (i & 31) * 2;
        *(float2*)&out[((size_t)(n * CC + j) << 14)
                       + (size_t)((h0 + (tl >> 3)) * WW + w0 + (tl & 7))] =
            *(const float2*)&tr_s[j * 68 + tl];
    }
}

extern "C" void kernel_launch(void* const* d_in, const int* in_sizes, int n_in,
                              void* d_out, int out_size, void* d_ws, size_t ws_size,
                              hipStream_t stream) {
    const float* x      = (const float*)d_in[0];
    const float* qkv_w  = (const float*)d_in[1];
    const float* qkv_b  = (const float*)d_in[2];
    const float* proj_w = (const float*)d_in[3];
    const float* proj_b = (const float*)d_in[4];
    const float* rpb    = (const float*)d_in[5];
    const float* ln1_w  = (const float*)d_in[6];
    const float* ln1_b  = (const float*)d_in[7];
    const float* ln2_w  = (const float*)d_in[8];
    const float* ln2_b  = (const float*)d_in[9];
    const float* fc1_w  = (const float*)d_in[10];
    const float* fc1_b  = (const float*)d_in[11];
    const float* fc2_w  = (const float*)d_in[12];
    const float* fc2_b  = (const float*)d_in[13];
    float* out = (float*)d_out;
    char* ws = (char*)d_ws;

    _Float16* qkv16  = (_Float16*)(ws);                 // 12.58 MB [T][192]
    _Float16* pw16   = (_Float16*)(ws + 20971520);      //  8 KB
    _Float16* f1w16  = (_Float16*)(ws + 20979712);      // 32 KB
    _Float16* f2w16  = (_Float16*)(ws + 21012480);      // 32 KB

    k_qkvln   <<<256, 512, 0, stream>>>(x, ln1_w, ln1_b, qkv_w, qkv_b,
                                        proj_w, fc1_w, fc2_w,
                                        qkv16, pw16, f1w16, f2w16);
    k_attn_mlp<<<512, 512, 0, stream>>>(qkv16, rpb, pw16, proj_b, x, ln2_w, ln2_b,
                                        f1w16, fc1_b, f2w16, fc2_b, out);
}